// Round 4
// baseline (841.470 us; speedup 1.0000x reference)
//
#include <hip/hip_runtime.h>

#define N_NODES 100000
#define N_EDGES 1600000
#define E_TOT   (N_EDGES + N_NODES)
#define NPART   8
#define PART_SZ (N_NODES / NPART)   // 12500
#define PART_BLOCKS 256             // blocks per partition

static __device__ __forceinline__ float lrelu(float z) { return z > 0.f ? z : 0.2f * z; }

// ---------------- CSR build (XCD-partitioned by dst range) ----------------
__global__ __launch_bounds__(256) void csr_count(const int* __restrict__ ei, int* __restrict__ cnt) {
    int part = blockIdx.x & (NPART - 1);
    int lo = part * PART_SZ, hi = lo + PART_SZ;
    int stride = (gridDim.x / NPART) * 256;
    for (int t = (blockIdx.x / NPART) * 256 + threadIdx.x; t < E_TOT; t += stride) {
        int d = (t < N_EDGES) ? ei[N_EDGES + t] : (t - N_EDGES);
        if (d >= lo && d < hi) atomicAdd(&cnt[d], 1);
    }
}

__global__ __launch_bounds__(256) void csr_scatter(const int* __restrict__ ei, int* __restrict__ cursor,
                                                   int* __restrict__ srcs) {
    int part = blockIdx.x & (NPART - 1);
    int lo = part * PART_SZ, hi = lo + PART_SZ;
    int stride = (gridDim.x / NPART) * 256;
    for (int t = (blockIdx.x / NPART) * 256 + threadIdx.x; t < E_TOT; t += stride) {
        int d = (t < N_EDGES) ? ei[N_EDGES + t] : (t - N_EDGES);
        if (d >= lo && d < hi) {
            int s = (t < N_EDGES) ? ei[t] : d;
            int pos = atomicAdd(&cursor[d], 1);
            srcs[pos] = s;
        }
    }
}

__global__ void scan1(const int* __restrict__ cnt, int* __restrict__ offs, int* __restrict__ bsum) {
    __shared__ int s[256];
    int t = threadIdx.x, i = blockIdx.x * 256 + t;
    int v = (i < N_NODES) ? cnt[i] : 0;
    s[t] = v; __syncthreads();
    for (int d = 1; d < 256; d <<= 1) {
        int a = (t >= d) ? s[t - d] : 0; __syncthreads();
        s[t] += a; __syncthreads();
    }
    if (i < N_NODES) offs[i] = s[t] - v;
    if (t == 255) bsum[blockIdx.x] = s[255];
}

__global__ void scan2(int* __restrict__ bsum, int nb) {
    __shared__ int s[512];
    int t = threadIdx.x;
    int v = (t < nb) ? bsum[t] : 0;
    s[t] = v; __syncthreads();
    for (int d = 1; d < 512; d <<= 1) {
        int a = (t >= d) ? s[t - d] : 0; __syncthreads();
        s[t] += a; __syncthreads();
    }
    if (t < nb) bsum[t] = s[t] - v;
}

__global__ void scan3(int* __restrict__ offs, const int* __restrict__ bsum, int* __restrict__ cursor) {
    int i = blockIdx.x * 256 + threadIdx.x;
    if (i < N_NODES) {
        int o = offs[i] + bsum[i >> 8];
        offs[i] = o;
        cursor[i] = o;
    }
    if (i == 0) offs[N_NODES] = E_TOT;
}

// ---------------- fused GEMM + attention logits (double-buffered pipeline) ----------------
// Round-3 version was phase-serial: stage -> sync -> compute (no loads in flight)
// => 695 GB/s achieved, VALUBusy 14%, 79 us. Now: store prefetch regs, issue
// float4 loads for chunk kc+1, sync, compute kc while loads fly. One sync/iter
// (store at iter k hits the buffer last READ at iter k-2; sync at k-1 separates).
template <int IN, int OUT, int HEADS>
__global__ __launch_bounds__(256) void gemm_al(const float* __restrict__ x, const float* __restrict__ W,
                                               const float* __restrict__ asrc, const float* __restrict__ adst,
                                               float* __restrict__ h, float* __restrict__ als,
                                               float* __restrict__ ald) {
    constexpr int KC = 32;
    constexpr int NCH = IN / KC;
    constexpr int C = OUT / HEADS;
    constexpr int TILE = 256 * 33;
    __shared__ float sx[2 * TILE];
    int t = threadIdx.x;
    int n = blockIdx.x * 256 + t;

    float acc[OUT];
#pragma unroll
    for (int j = 0; j < OUT; ++j) acc[j] = 0.f;

    float4 r[8];
    // prologue: load chunk 0 (pass p: element e = p*256+t; row=e>>3, c4=e&7)
#pragma unroll
    for (int p = 0; p < 8; ++p) {
        int e = p * 256 + t;
        int row = blockIdx.x * 256 + (e >> 3);
        if (row >= N_NODES) row = N_NODES - 1;
        r[p] = *reinterpret_cast<const float4*>(&x[(long)row * IN + (e & 7) * 4]);
    }

    int b = 0;
#pragma unroll
    for (int kc = 0; kc < NCH; ++kc) {
        // store prefetched chunk into buffer b
#pragma unroll
        for (int p = 0; p < 8; ++p) {
            int e = p * 256 + t;
            float* d = &sx[b * TILE + (e >> 3) * 33 + (e & 7) * 4];
            d[0] = r[p].x; d[1] = r[p].y; d[2] = r[p].z; d[3] = r[p].w;
        }
        // issue loads for chunk kc+1 (in flight during compute below)
        if (kc + 1 < NCH) {
#pragma unroll
            for (int p = 0; p < 8; ++p) {
                int e = p * 256 + t;
                int row = blockIdx.x * 256 + (e >> 3);
                if (row >= N_NODES) row = N_NODES - 1;
                r[p] = *reinterpret_cast<const float4*>(&x[(long)row * IN + (kc + 1) * KC + (e & 7) * 4]);
            }
        }
        __syncthreads();
#pragma unroll
        for (int k = 0; k < KC; ++k) {
            float xv = sx[b * TILE + t * 33 + k];
            const float* Wr = W + (kc * KC + k) * OUT;  // wave-uniform -> scalar loads
#pragma unroll
            for (int j = 0; j < OUT; ++j) acc[j] = fmaf(xv, Wr[j], acc[j]);
        }
        b ^= 1;
    }

    if (n < N_NODES) {
#pragma unroll
        for (int j = 0; j < OUT; j += 4) {
            float4 v = make_float4(acc[j], acc[j + 1], acc[j + 2], acc[j + 3]);
            *reinterpret_cast<float4*>(&h[(long)n * OUT + j]) = v;
        }
#pragma unroll
        for (int hd = 0; hd < HEADS; ++hd) {
            float ps = 0.f, pd = 0.f;
#pragma unroll
            for (int c = 0; c < C; ++c) {
                ps = fmaf(acc[hd * C + c], asrc[hd * C + c], ps);
                pd = fmaf(acc[hd * C + c], adst[hd * C + c], pd);
            }
            als[n * HEADS + hd] = ps;
            ald[n * HEADS + hd] = pd;
        }
    }
}

// ---------------- aggregation, H=4 C=16 ----------------
// wave per dst node; q=lane>>4 = edge slot (4 edges in flight),
// cc=lane&15 = float4 channel slice (16 lanes x 16B = full 64-ch row).
__global__ __launch_bounds__(256) void agg_h4(const int* __restrict__ offs, const int* __restrict__ srcs,
                                              const float* __restrict__ h, const float* __restrict__ als,
                                              const float* __restrict__ ald, const float* __restrict__ bias,
                                              float* __restrict__ g, int do_relu) {
    int wid = threadIdx.x >> 6, lane = threadIdx.x & 63;
    int n = blockIdx.x * 4 + wid;
    if (n >= N_NODES) return;
    int q = lane >> 4, cc = lane & 15;
    int hd = cc >> 2;
    float ad = ald[n * 4 + hd];
    int e0 = offs[n], e1 = offs[n + 1];
    float4 acc = make_float4(0.f, 0.f, 0.f, 0.f);
    float den = 0.f;
    for (int e = e0; e < e1; e += 4) {
        int ee = e + q;
        int idx = (ee < e1) ? ee : (e1 - 1);
        int s = srcs[idx];
        float w = __expf(lrelu(als[s * 4 + hd] + ad));
        w = (ee < e1) ? w : 0.f;
        float4 hv = *reinterpret_cast<const float4*>(&h[(long)s * 64 + cc * 4]);
        den += w;
        acc.x = fmaf(w, hv.x, acc.x);
        acc.y = fmaf(w, hv.y, acc.y);
        acc.z = fmaf(w, hv.z, acc.z);
        acc.w = fmaf(w, hv.w, acc.w);
    }
    acc.x += __shfl_xor(acc.x, 16); acc.y += __shfl_xor(acc.y, 16);
    acc.z += __shfl_xor(acc.z, 16); acc.w += __shfl_xor(acc.w, 16);
    den += __shfl_xor(den, 16);
    acc.x += __shfl_xor(acc.x, 32); acc.y += __shfl_xor(acc.y, 32);
    acc.z += __shfl_xor(acc.z, 32); acc.w += __shfl_xor(acc.w, 32);
    den += __shfl_xor(den, 32);
    if (q == 0) {
        float4 b4 = *reinterpret_cast<const float4*>(&bias[cc * 4]);
        float inv = 1.f / den;
        float4 o;
        o.x = fmaf(acc.x, inv, b4.x);
        o.y = fmaf(acc.y, inv, b4.y);
        o.z = fmaf(acc.z, inv, b4.z);
        o.w = fmaf(acc.w, inv, b4.w);
        if (do_relu) {
            o.x = fmaxf(o.x, 0.f); o.y = fmaxf(o.y, 0.f);
            o.z = fmaxf(o.z, 0.f); o.w = fmaxf(o.w, 0.f);
        }
        *reinterpret_cast<float4*>(&g[(long)n * 64 + cc * 4]) = o;
    }
}

// ---------------- aggregation, H=1 C=32 ----------------
__global__ __launch_bounds__(256) void agg_h1(const int* __restrict__ offs, const int* __restrict__ srcs,
                                              const float* __restrict__ h3, const float* __restrict__ als,
                                              const float* __restrict__ ald, const float* __restrict__ bias,
                                              float* __restrict__ out) {
    int wid = threadIdx.x >> 6, lane = threadIdx.x & 63;
    int n = blockIdx.x * 4 + wid;
    if (n >= N_NODES) return;
    int q = lane >> 3, cc = lane & 7;
    float ad = ald[n];
    int e0 = offs[n], e1 = offs[n + 1];
    float4 acc = make_float4(0.f, 0.f, 0.f, 0.f);
    float den = 0.f;
    for (int e = e0; e < e1; e += 8) {
        int ee = e + q;
        int idx = (ee < e1) ? ee : (e1 - 1);
        int s = srcs[idx];
        float w = __expf(lrelu(als[s] + ad));
        w = (ee < e1) ? w : 0.f;
        float4 hv = *reinterpret_cast<const float4*>(&h3[(long)s * 32 + cc * 4]);
        den += w;
        acc.x = fmaf(w, hv.x, acc.x);
        acc.y = fmaf(w, hv.y, acc.y);
        acc.z = fmaf(w, hv.z, acc.z);
        acc.w = fmaf(w, hv.w, acc.w);
    }
    acc.x += __shfl_xor(acc.x, 8);  acc.y += __shfl_xor(acc.y, 8);
    acc.z += __shfl_xor(acc.z, 8);  acc.w += __shfl_xor(acc.w, 8);
    den += __shfl_xor(den, 8);
    acc.x += __shfl_xor(acc.x, 16); acc.y += __shfl_xor(acc.y, 16);
    acc.z += __shfl_xor(acc.z, 16); acc.w += __shfl_xor(acc.w, 16);
    den += __shfl_xor(den, 16);
    acc.x += __shfl_xor(acc.x, 32); acc.y += __shfl_xor(acc.y, 32);
    acc.z += __shfl_xor(acc.z, 32); acc.w += __shfl_xor(acc.w, 32);
    den += __shfl_xor(den, 32);
    if (q == 0) {
        float4 b4 = *reinterpret_cast<const float4*>(&bias[cc * 4]);
        float inv = 1.f / den;
        float4 o;
        o.x = fmaf(acc.x, inv, b4.x);
        o.y = fmaf(acc.y, inv, b4.y);
        o.z = fmaf(acc.z, inv, b4.z);
        o.w = fmaf(acc.w, inv, b4.w);
        *reinterpret_cast<float4*>(&out[(long)n * 32 + cc * 4]) = o;
    }
}

extern "C" void kernel_launch(void* const* d_in, const int* in_sizes, int n_in,
                              void* d_out, int out_size, void* d_ws, size_t ws_size,
                              hipStream_t stream) {
    (void)in_sizes; (void)n_in; (void)out_size; (void)ws_size;
    const float* x   = (const float*)d_in[0];
    const int*   ei  = (const int*)d_in[1];
    const float* W1  = (const float*)d_in[2];
    const float* as1 = (const float*)d_in[3];
    const float* ad1 = (const float*)d_in[4];
    const float* b1  = (const float*)d_in[5];
    const float* W2  = (const float*)d_in[6];
    const float* as2 = (const float*)d_in[7];
    const float* ad2 = (const float*)d_in[8];
    const float* b2  = (const float*)d_in[9];
    const float* W3  = (const float*)d_in[10];
    const float* as3 = (const float*)d_in[11];
    const float* ad3 = (const float*)d_in[12];
    const float* b3  = (const float*)d_in[13];
    float* out = (float*)d_out;

    char* w = (char*)d_ws;
    auto alloc = [&](size_t bytes) {
        void* p = (void*)w;
        w += (bytes + 255) & ~(size_t)255;
        return p;
    };
    int*   cnt    = (int*)alloc((size_t)N_NODES * 4);
    int*   offs   = (int*)alloc((size_t)(N_NODES + 1) * 4);
    int*   bsum   = (int*)alloc(512 * 4);
    int*   cursor = (int*)alloc((size_t)N_NODES * 4);
    int*   srcs   = (int*)alloc((size_t)E_TOT * 4);
    float* h      = (float*)alloc((size_t)N_NODES * 64 * 4);
    float* g      = (float*)alloc((size_t)N_NODES * 64 * 4);
    float* als    = (float*)alloc((size_t)N_NODES * 4 * 4);
    float* ald    = (float*)alloc((size_t)N_NODES * 4 * 4);

    hipMemsetAsync(cnt, 0, (size_t)N_NODES * 4, stream);

    int gN = (N_NODES + 255) / 256;   // 391
    csr_count<<<NPART * PART_BLOCKS, 256, 0, stream>>>(ei, cnt);
    scan1<<<gN, 256, 0, stream>>>(cnt, offs, bsum);
    scan2<<<1, 512, 0, stream>>>(bsum, gN);
    scan3<<<gN, 256, 0, stream>>>(offs, bsum, cursor);
    csr_scatter<<<NPART * PART_BLOCKS, 256, 0, stream>>>(ei, cursor, srcs);

    // layer 1: x[100000,128] @ W1[128,64], H=4
    gemm_al<128, 64, 4><<<gN, 256, 0, stream>>>(x, W1, as1, ad1, h, als, ald);
    agg_h4<<<N_NODES / 4, 256, 0, stream>>>(offs, srcs, h, als, ald, b1, g, 1);
    // layer 2: g[100000,64] @ W2[64,64], H=4
    gemm_al<64, 64, 4><<<gN, 256, 0, stream>>>(g, W2, as2, ad2, h, als, ald);
    agg_h4<<<N_NODES / 4, 256, 0, stream>>>(offs, srcs, h, als, ald, b2, g, 1);
    // layer 3: g[100000,64] @ W3[64,32], H=1 -> d_out
    gemm_al<64, 32, 1><<<gN, 256, 0, stream>>>(g, W3, as3, ad3, h, als, ald);
    agg_h1<<<N_NODES / 4, 256, 0, stream>>>(offs, srcs, h, als, ald, b3, out);
}

// Round 5
// 663.040 us; speedup vs baseline: 1.2691x; 1.2691x over previous
//
#include <hip/hip_runtime.h>

#define N_NODES 100000
#define N_EDGES 1600000
#define E_TOT   (N_EDGES + N_NODES)
#define NPART   8
#define PART_SZ (N_NODES / NPART)   // 12500
#define PART_BLOCKS 256             // blocks per partition

static __device__ __forceinline__ float lrelu(float z) { return z > 0.f ? z : 0.2f * z; }

// ---------------- CSR build (XCD-partitioned by dst range) ----------------
__global__ __launch_bounds__(256) void csr_count(const int* __restrict__ ei, int* __restrict__ cnt) {
    int part = blockIdx.x & (NPART - 1);
    int lo = part * PART_SZ, hi = lo + PART_SZ;
    int stride = (gridDim.x / NPART) * 256;
    for (int t = (blockIdx.x / NPART) * 256 + threadIdx.x; t < E_TOT; t += stride) {
        int d = (t < N_EDGES) ? ei[N_EDGES + t] : (t - N_EDGES);
        if (d >= lo && d < hi) atomicAdd(&cnt[d], 1);
    }
}

__global__ __launch_bounds__(256) void csr_scatter(const int* __restrict__ ei, int* __restrict__ cursor,
                                                   int* __restrict__ srcs) {
    int part = blockIdx.x & (NPART - 1);
    int lo = part * PART_SZ, hi = lo + PART_SZ;
    int stride = (gridDim.x / NPART) * 256;
    for (int t = (blockIdx.x / NPART) * 256 + threadIdx.x; t < E_TOT; t += stride) {
        int d = (t < N_EDGES) ? ei[N_EDGES + t] : (t - N_EDGES);
        if (d >= lo && d < hi) {
            int s = (t < N_EDGES) ? ei[t] : d;
            int pos = atomicAdd(&cursor[d], 1);
            srcs[pos] = s;
        }
    }
}

__global__ void scan1(const int* __restrict__ cnt, int* __restrict__ offs, int* __restrict__ bsum) {
    __shared__ int s[256];
    int t = threadIdx.x, i = blockIdx.x * 256 + t;
    int v = (i < N_NODES) ? cnt[i] : 0;
    s[t] = v; __syncthreads();
    for (int d = 1; d < 256; d <<= 1) {
        int a = (t >= d) ? s[t - d] : 0; __syncthreads();
        s[t] += a; __syncthreads();
    }
    if (i < N_NODES) offs[i] = s[t] - v;
    if (t == 255) bsum[blockIdx.x] = s[255];
}

__global__ void scan2(int* __restrict__ bsum, int nb) {
    __shared__ int s[512];
    int t = threadIdx.x;
    int v = (t < nb) ? bsum[t] : 0;
    s[t] = v; __syncthreads();
    for (int d = 1; d < 512; d <<= 1) {
        int a = (t >= d) ? s[t - d] : 0; __syncthreads();
        s[t] += a; __syncthreads();
    }
    if (t < nb) bsum[t] = s[t] - v;
}

__global__ void scan3(int* __restrict__ offs, const int* __restrict__ bsum, int* __restrict__ cursor) {
    int i = blockIdx.x * 256 + threadIdx.x;
    if (i < N_NODES) {
        int o = offs[i] + bsum[i >> 8];
        offs[i] = o;
        cursor[i] = o;
    }
    if (i == 0) offs[N_NODES] = E_TOT;
}

// ---------------- fused GEMM + attention logits (wave-sliced) ----------------
// Round-3 was thread-per-node (acc[64]) => only 1563 waves TOTAL (1.5/SIMD),
// latency-bound at 695 GB/s. Round-4 double-buffering failed: compiler drains
// vmcnt(0) at every s_barrier, so cross-barrier prefetch is impossible.
// Now: wave = (64 nodes) x (wave-uniform 16-col output slice). W stays
// wave-uniform (scalar s_loads), 4x the waves, acc[16], ONE barrier total.
// LDS x-tile stride IN+1: compute read bank = (row+k)%32, 2-way = free (m136).
template <int IN, int OUT, int HEADS, int NPB>
__global__ __launch_bounds__(256) void gemm_al(const float* __restrict__ x, const float* __restrict__ W,
                                               const float* __restrict__ asrc, const float* __restrict__ adst,
                                               float* __restrict__ h, float* __restrict__ als,
                                               float* __restrict__ ald) {
    constexpr int SPLIT = OUT / 16;          // output slices (waves per node-group)
    constexpr int STRIDE = IN + 1;
    constexpr int F4PT = NPB * (IN / 4) / 256;  // float4 loads per thread
    __shared__ float sx[NPB * STRIDE];
    int t = threadIdx.x;
    long base = (long)blockIdx.x * NPB;

    // stage x-tile: coalesced float4 global loads, scalar LDS stores
#pragma unroll
    for (int p = 0; p < F4PT; ++p) {
        int e = p * 256 + t;
        int row = e / (IN / 4);
        int c4 = e % (IN / 4);
        long gr = base + row;
        if (gr >= N_NODES) gr = N_NODES - 1;
        float4 v = *reinterpret_cast<const float4*>(&x[gr * IN + c4 * 4]);
        float* d = &sx[row * STRIDE + c4 * 4];
        d[0] = v.x; d[1] = v.y; d[2] = v.z; d[3] = v.w;
    }
    __syncthreads();

    int w = t >> 6, lane = t & 63;
    int s = w % SPLIT;             // wave-uniform output slice
    int grp = w / SPLIT;
    int r = grp * 64 + lane;       // local node row
    long n = base + r;

    float acc[16];
#pragma unroll
    for (int j = 0; j < 16; ++j) acc[j] = 0.f;

    const float* Ws = W + s * 16;  // wave-uniform
#pragma unroll 8
    for (int k = 0; k < IN; ++k) {
        float xv = sx[r * STRIDE + k];
        const float* Wr = Ws + k * OUT;   // wave-uniform -> s_load
#pragma unroll
        for (int j = 0; j < 16; ++j) acc[j] = fmaf(xv, Wr[j], acc[j]);
    }

    if (n < N_NODES) {
#pragma unroll
        for (int j = 0; j < 16; j += 4) {
            *reinterpret_cast<float4*>(&h[n * OUT + s * 16 + j]) =
                make_float4(acc[j], acc[j + 1], acc[j + 2], acc[j + 3]);
        }
    }

    // attention logits
    float ps = 0.f, pd = 0.f;
#pragma unroll
    for (int j = 0; j < 16; ++j) {
        ps = fmaf(acc[j], asrc[s * 16 + j], ps);
        pd = fmaf(acc[j], adst[s * 16 + j], pd);
    }
    if (HEADS == SPLIT) {
        // C==16: slice s IS head s -> direct store, no reduction
        if (n < N_NODES) {
            als[n * HEADS + s] = ps;
            ald[n * HEADS + s] = pd;
        }
    } else {
        // HEADS==1, SPLIT==2 (C==32): combine the two slices via LDS
        __syncthreads();                 // all compute reads of sx done
        sx[r * 2 + s] = ps;
        sx[NPB * 2 + r * 2 + s] = pd;
        __syncthreads();
        if (t < NPB) {
            long nn = base + t;
            if (nn < N_NODES) {
                als[nn] = sx[t * 2] + sx[t * 2 + 1];
                ald[nn] = sx[NPB * 2 + t * 2] + sx[NPB * 2 + t * 2 + 1];
            }
        }
    }
}

// ---------------- aggregation, H=4 C=16 ----------------
// wave per dst node; q=lane>>4 = edge slot (4 edges in flight),
// cc=lane&15 = float4 channel slice (16 lanes x 16B = full 64-ch row).
__global__ __launch_bounds__(256) void agg_h4(const int* __restrict__ offs, const int* __restrict__ srcs,
                                              const float* __restrict__ h, const float* __restrict__ als,
                                              const float* __restrict__ ald, const float* __restrict__ bias,
                                              float* __restrict__ g, int do_relu) {
    int wid = threadIdx.x >> 6, lane = threadIdx.x & 63;
    int n = blockIdx.x * 4 + wid;
    if (n >= N_NODES) return;
    int q = lane >> 4, cc = lane & 15;
    int hd = cc >> 2;
    float ad = ald[n * 4 + hd];
    int e0 = offs[n], e1 = offs[n + 1];
    float4 acc = make_float4(0.f, 0.f, 0.f, 0.f);
    float den = 0.f;
    for (int e = e0; e < e1; e += 4) {
        int ee = e + q;
        int idx = (ee < e1) ? ee : (e1 - 1);
        int s = srcs[idx];
        float w = __expf(lrelu(als[s * 4 + hd] + ad));
        w = (ee < e1) ? w : 0.f;
        float4 hv = *reinterpret_cast<const float4*>(&h[(long)s * 64 + cc * 4]);
        den += w;
        acc.x = fmaf(w, hv.x, acc.x);
        acc.y = fmaf(w, hv.y, acc.y);
        acc.z = fmaf(w, hv.z, acc.z);
        acc.w = fmaf(w, hv.w, acc.w);
    }
    acc.x += __shfl_xor(acc.x, 16); acc.y += __shfl_xor(acc.y, 16);
    acc.z += __shfl_xor(acc.z, 16); acc.w += __shfl_xor(acc.w, 16);
    den += __shfl_xor(den, 16);
    acc.x += __shfl_xor(acc.x, 32); acc.y += __shfl_xor(acc.y, 32);
    acc.z += __shfl_xor(acc.z, 32); acc.w += __shfl_xor(acc.w, 32);
    den += __shfl_xor(den, 32);
    if (q == 0) {
        float4 b4 = *reinterpret_cast<const float4*>(&bias[cc * 4]);
        float inv = 1.f / den;
        float4 o;
        o.x = fmaf(acc.x, inv, b4.x);
        o.y = fmaf(acc.y, inv, b4.y);
        o.z = fmaf(acc.z, inv, b4.z);
        o.w = fmaf(acc.w, inv, b4.w);
        if (do_relu) {
            o.x = fmaxf(o.x, 0.f); o.y = fmaxf(o.y, 0.f);
            o.z = fmaxf(o.z, 0.f); o.w = fmaxf(o.w, 0.f);
        }
        *reinterpret_cast<float4*>(&g[(long)n * 64 + cc * 4]) = o;
    }
}

// ---------------- aggregation, H=1 C=32 ----------------
__global__ __launch_bounds__(256) void agg_h1(const int* __restrict__ offs, const int* __restrict__ srcs,
                                              const float* __restrict__ h3, const float* __restrict__ als,
                                              const float* __restrict__ ald, const float* __restrict__ bias,
                                              float* __restrict__ out) {
    int wid = threadIdx.x >> 6, lane = threadIdx.x & 63;
    int n = blockIdx.x * 4 + wid;
    if (n >= N_NODES) return;
    int q = lane >> 3, cc = lane & 7;
    float ad = ald[n];
    int e0 = offs[n], e1 = offs[n + 1];
    float4 acc = make_float4(0.f, 0.f, 0.f, 0.f);
    float den = 0.f;
    for (int e = e0; e < e1; e += 8) {
        int ee = e + q;
        int idx = (ee < e1) ? ee : (e1 - 1);
        int s = srcs[idx];
        float w = __expf(lrelu(als[s] + ad));
        w = (ee < e1) ? w : 0.f;
        float4 hv = *reinterpret_cast<const float4*>(&h3[(long)s * 32 + cc * 4]);
        den += w;
        acc.x = fmaf(w, hv.x, acc.x);
        acc.y = fmaf(w, hv.y, acc.y);
        acc.z = fmaf(w, hv.z, acc.z);
        acc.w = fmaf(w, hv.w, acc.w);
    }
    acc.x += __shfl_xor(acc.x, 8);  acc.y += __shfl_xor(acc.y, 8);
    acc.z += __shfl_xor(acc.z, 8);  acc.w += __shfl_xor(acc.w, 8);
    den += __shfl_xor(den, 8);
    acc.x += __shfl_xor(acc.x, 16); acc.y += __shfl_xor(acc.y, 16);
    acc.z += __shfl_xor(acc.z, 16); acc.w += __shfl_xor(acc.w, 16);
    den += __shfl_xor(den, 16);
    acc.x += __shfl_xor(acc.x, 32); acc.y += __shfl_xor(acc.y, 32);
    acc.z += __shfl_xor(acc.z, 32); acc.w += __shfl_xor(acc.w, 32);
    den += __shfl_xor(den, 32);
    if (q == 0) {
        float4 b4 = *reinterpret_cast<const float4*>(&bias[cc * 4]);
        float inv = 1.f / den;
        float4 o;
        o.x = fmaf(acc.x, inv, b4.x);
        o.y = fmaf(acc.y, inv, b4.y);
        o.z = fmaf(acc.z, inv, b4.z);
        o.w = fmaf(acc.w, inv, b4.w);
        *reinterpret_cast<float4*>(&out[(long)n * 32 + cc * 4]) = o;
    }
}

extern "C" void kernel_launch(void* const* d_in, const int* in_sizes, int n_in,
                              void* d_out, int out_size, void* d_ws, size_t ws_size,
                              hipStream_t stream) {
    (void)in_sizes; (void)n_in; (void)out_size; (void)ws_size;
    const float* x   = (const float*)d_in[0];
    const int*   ei  = (const int*)d_in[1];
    const float* W1  = (const float*)d_in[2];
    const float* as1 = (const float*)d_in[3];
    const float* ad1 = (const float*)d_in[4];
    const float* b1  = (const float*)d_in[5];
    const float* W2  = (const float*)d_in[6];
    const float* as2 = (const float*)d_in[7];
    const float* ad2 = (const float*)d_in[8];
    const float* b2  = (const float*)d_in[9];
    const float* W3  = (const float*)d_in[10];
    const float* as3 = (const float*)d_in[11];
    const float* ad3 = (const float*)d_in[12];
    const float* b3  = (const float*)d_in[13];
    float* out = (float*)d_out;

    char* w = (char*)d_ws;
    auto alloc = [&](size_t bytes) {
        void* p = (void*)w;
        w += (bytes + 255) & ~(size_t)255;
        return p;
    };
    int*   cnt    = (int*)alloc((size_t)N_NODES * 4);
    int*   offs   = (int*)alloc((size_t)(N_NODES + 1) * 4);
    int*   bsum   = (int*)alloc(512 * 4);
    int*   cursor = (int*)alloc((size_t)N_NODES * 4);
    int*   srcs   = (int*)alloc((size_t)E_TOT * 4);
    float* h      = (float*)alloc((size_t)N_NODES * 64 * 4);
    float* g      = (float*)alloc((size_t)N_NODES * 64 * 4);
    float* als    = (float*)alloc((size_t)N_NODES * 4 * 4);
    float* ald    = (float*)alloc((size_t)N_NODES * 4 * 4);

    hipMemsetAsync(cnt, 0, (size_t)N_NODES * 4, stream);

    int gN = (N_NODES + 255) / 256;   // 391
    csr_count<<<NPART * PART_BLOCKS, 256, 0, stream>>>(ei, cnt);
    scan1<<<gN, 256, 0, stream>>>(cnt, offs, bsum);
    scan2<<<1, 512, 0, stream>>>(bsum, gN);
    scan3<<<gN, 256, 0, stream>>>(offs, bsum, cursor);
    csr_scatter<<<NPART * PART_BLOCKS, 256, 0, stream>>>(ei, cursor, srcs);

    int g64  = (N_NODES + 63) / 64;    // 1563
    int g128 = (N_NODES + 127) / 128;  // 782
    // layer 1: x[100000,128] @ W1[128,64], H=4
    gemm_al<128, 64, 4, 64><<<g64, 256, 0, stream>>>(x, W1, as1, ad1, h, als, ald);
    agg_h4<<<N_NODES / 4, 256, 0, stream>>>(offs, srcs, h, als, ald, b1, g, 1);
    // layer 2: g[100000,64] @ W2[64,64], H=4
    gemm_al<64, 64, 4, 64><<<g64, 256, 0, stream>>>(g, W2, as2, ad2, h, als, ald);
    agg_h4<<<N_NODES / 4, 256, 0, stream>>>(offs, srcs, h, als, ald, b2, g, 1);
    // layer 3: g[100000,64] @ W3[64,32], H=1 -> d_out
    gemm_al<64, 32, 1, 128><<<g128, 256, 0, stream>>>(g, W3, as3, ad3, h, als, ald);
    agg_h1<<<N_NODES / 4, 256, 0, stream>>>(offs, srcs, h, als, ald, b3, out);
}

// Round 6
// 518.374 us; speedup vs baseline: 1.6233x; 1.2791x over previous
//
#include <hip/hip_runtime.h>

#define N_NODES 100000
#define N_EDGES 1600000
#define E_TOT   (N_EDGES + N_NODES)
#define NPART   8
#define PART_SZ (N_NODES / NPART)   // 12500
#define PART_BLOCKS 256             // blocks per partition

static __device__ __forceinline__ float lrelu(float z) { return z > 0.f ? z : 0.2f * z; }

// ---------------- CSR build (XCD-partitioned by dst range) ----------------
__global__ __launch_bounds__(256) void csr_count(const int* __restrict__ ei, int* __restrict__ cnt) {
    int part = blockIdx.x & (NPART - 1);
    int lo = part * PART_SZ, hi = lo + PART_SZ;
    int stride = (gridDim.x / NPART) * 256;
    for (int t = (blockIdx.x / NPART) * 256 + threadIdx.x; t < E_TOT; t += stride) {
        int d = (t < N_EDGES) ? ei[N_EDGES + t] : (t - N_EDGES);
        if (d >= lo && d < hi) atomicAdd(&cnt[d], 1);
    }
}

__global__ __launch_bounds__(256) void csr_scatter(const int* __restrict__ ei, int* __restrict__ cursor,
                                                   int* __restrict__ srcs) {
    int part = blockIdx.x & (NPART - 1);
    int lo = part * PART_SZ, hi = lo + PART_SZ;
    int stride = (gridDim.x / NPART) * 256;
    for (int t = (blockIdx.x / NPART) * 256 + threadIdx.x; t < E_TOT; t += stride) {
        int d = (t < N_EDGES) ? ei[N_EDGES + t] : (t - N_EDGES);
        if (d >= lo && d < hi) {
            int s = (t < N_EDGES) ? ei[t] : d;
            int pos = atomicAdd(&cursor[d], 1);
            srcs[pos] = s;
        }
    }
}

__global__ void scan1(const int* __restrict__ cnt, int* __restrict__ offs, int* __restrict__ bsum) {
    __shared__ int s[256];
    int t = threadIdx.x, i = blockIdx.x * 256 + t;
    int v = (i < N_NODES) ? cnt[i] : 0;
    s[t] = v; __syncthreads();
    for (int d = 1; d < 256; d <<= 1) {
        int a = (t >= d) ? s[t - d] : 0; __syncthreads();
        s[t] += a; __syncthreads();
    }
    if (i < N_NODES) offs[i] = s[t] - v;
    if (t == 255) bsum[blockIdx.x] = s[255];
}

__global__ void scan2(int* __restrict__ bsum, int nb) {
    __shared__ int s[512];
    int t = threadIdx.x;
    int v = (t < nb) ? bsum[t] : 0;
    s[t] = v; __syncthreads();
    for (int d = 1; d < 512; d <<= 1) {
        int a = (t >= d) ? s[t - d] : 0; __syncthreads();
        s[t] += a; __syncthreads();
    }
    if (t < nb) bsum[t] = s[t] - v;
}

__global__ void scan3(int* __restrict__ offs, const int* __restrict__ bsum, int* __restrict__ cursor) {
    int i = blockIdx.x * 256 + threadIdx.x;
    if (i < N_NODES) {
        int o = offs[i] + bsum[i >> 8];
        offs[i] = o;
        cursor[i] = o;
    }
    if (i == 0) offs[N_NODES] = E_TOT;
}

// ---------------- fused GEMM + attention logits (wave-sliced, scalar W path) ----------------
// Round-5 lesson: s = (threadIdx>>6)%SPLIT is NOT provably wave-uniform, so W
// indexing compiled to per-lane global_load broadcasts (2048 VMEM/thread,
// VALUBusy 9%). readfirstlane(s) forces the whole W address chain into SGPRs
// -> s_load_dwordx16 per k-row on the SMEM pipe. LDS x-tile stride IN+1 keeps
// the hot-loop read at 2-way bank aliasing (free, m136).
template <int IN, int OUT, int HEADS, int NPB>
__global__ __launch_bounds__(256) void gemm_al(const float* __restrict__ x, const float* __restrict__ W,
                                               const float* __restrict__ asrc, const float* __restrict__ adst,
                                               float* __restrict__ h, float* __restrict__ als,
                                               float* __restrict__ ald) {
    constexpr int SPLIT = OUT / 16;          // output slices (waves per node-group)
    constexpr int STRIDE = IN + 1;
    constexpr int F4PT = NPB * (IN / 4) / 256;  // float4 loads per thread
    __shared__ float sx[NPB * STRIDE];
    int t = threadIdx.x;
    long base = (long)blockIdx.x * NPB;

    // stage x-tile: coalesced float4 global loads, scalar LDS stores
#pragma unroll
    for (int p = 0; p < F4PT; ++p) {
        int e = p * 256 + t;
        int row = e / (IN / 4);
        int c4 = e % (IN / 4);
        long gr = base + row;
        if (gr >= N_NODES) gr = N_NODES - 1;
        float4 v = *reinterpret_cast<const float4*>(&x[gr * IN + c4 * 4]);
        float* d = &sx[row * STRIDE + c4 * 4];
        d[0] = v.x; d[1] = v.y; d[2] = v.z; d[3] = v.w;
    }
    __syncthreads();

    int w = t >> 6, lane = t & 63;
    int s = __builtin_amdgcn_readfirstlane(w % SPLIT);   // wave-uniform -> SGPR
    int grp = __builtin_amdgcn_readfirstlane(w / SPLIT);
    int r = grp * 64 + lane;       // local node row
    long n = base + r;

    float acc[16];
#pragma unroll
    for (int j = 0; j < 16; ++j) acc[j] = 0.f;

    const float* Ws = W + s * 16;  // SGPR base
#pragma unroll 8
    for (int k = 0; k < IN; ++k) {
        float xv = sx[r * STRIDE + k];
        const float* Wr = Ws + k * OUT;   // uniform -> s_load_dwordx16
#pragma unroll
        for (int j = 0; j < 16; ++j) acc[j] = fmaf(xv, Wr[j], acc[j]);
    }

    if (n < N_NODES) {
#pragma unroll
        for (int j = 0; j < 16; j += 4) {
            *reinterpret_cast<float4*>(&h[n * OUT + s * 16 + j]) =
                make_float4(acc[j], acc[j + 1], acc[j + 2], acc[j + 3]);
        }
    }

    // attention logits
    float ps = 0.f, pd = 0.f;
#pragma unroll
    for (int j = 0; j < 16; ++j) {
        ps = fmaf(acc[j], asrc[s * 16 + j], ps);
        pd = fmaf(acc[j], adst[s * 16 + j], pd);
    }
    if (HEADS == SPLIT) {
        // C==16: slice s IS head s -> direct store, no reduction
        if (n < N_NODES) {
            als[n * HEADS + s] = ps;
            ald[n * HEADS + s] = pd;
        }
    } else {
        // HEADS==1, SPLIT==2 (C==32): combine the two slices via LDS
        __syncthreads();                 // all compute reads of sx done
        sx[r * 2 + s] = ps;
        sx[NPB * 2 + r * 2 + s] = pd;
        __syncthreads();
        if (t < NPB) {
            long nn = base + t;
            if (nn < N_NODES) {
                als[nn] = sx[t * 2] + sx[t * 2 + 1];
                ald[nn] = sx[NPB * 2 + t * 2] + sx[NPB * 2 + t * 2 + 1];
            }
        }
    }
}

// ---------------- aggregation, H=4 C=16 ----------------
// wave per dst node; q=lane>>4 = edge slot (4 edges in flight),
// cc=lane&15 = float4 channel slice (16 lanes x 16B = full 64-ch row).
__global__ __launch_bounds__(256) void agg_h4(const int* __restrict__ offs, const int* __restrict__ srcs,
                                              const float* __restrict__ h, const float* __restrict__ als,
                                              const float* __restrict__ ald, const float* __restrict__ bias,
                                              float* __restrict__ g, int do_relu) {
    int wid = threadIdx.x >> 6, lane = threadIdx.x & 63;
    int n = blockIdx.x * 4 + wid;
    if (n >= N_NODES) return;
    int q = lane >> 4, cc = lane & 15;
    int hd = cc >> 2;
    float ad = ald[n * 4 + hd];
    int e0 = offs[n], e1 = offs[n + 1];
    float4 acc = make_float4(0.f, 0.f, 0.f, 0.f);
    float den = 0.f;
    for (int e = e0; e < e1; e += 4) {
        int ee = e + q;
        int idx = (ee < e1) ? ee : (e1 - 1);
        int s = srcs[idx];
        float w = __expf(lrelu(als[s * 4 + hd] + ad));
        w = (ee < e1) ? w : 0.f;
        float4 hv = *reinterpret_cast<const float4*>(&h[(long)s * 64 + cc * 4]);
        den += w;
        acc.x = fmaf(w, hv.x, acc.x);
        acc.y = fmaf(w, hv.y, acc.y);
        acc.z = fmaf(w, hv.z, acc.z);
        acc.w = fmaf(w, hv.w, acc.w);
    }
    acc.x += __shfl_xor(acc.x, 16); acc.y += __shfl_xor(acc.y, 16);
    acc.z += __shfl_xor(acc.z, 16); acc.w += __shfl_xor(acc.w, 16);
    den += __shfl_xor(den, 16);
    acc.x += __shfl_xor(acc.x, 32); acc.y += __shfl_xor(acc.y, 32);
    acc.z += __shfl_xor(acc.z, 32); acc.w += __shfl_xor(acc.w, 32);
    den += __shfl_xor(den, 32);
    if (q == 0) {
        float4 b4 = *reinterpret_cast<const float4*>(&bias[cc * 4]);
        float inv = 1.f / den;
        float4 o;
        o.x = fmaf(acc.x, inv, b4.x);
        o.y = fmaf(acc.y, inv, b4.y);
        o.z = fmaf(acc.z, inv, b4.z);
        o.w = fmaf(acc.w, inv, b4.w);
        if (do_relu) {
            o.x = fmaxf(o.x, 0.f); o.y = fmaxf(o.y, 0.f);
            o.z = fmaxf(o.z, 0.f); o.w = fmaxf(o.w, 0.f);
        }
        *reinterpret_cast<float4*>(&g[(long)n * 64 + cc * 4]) = o;
    }
}

// ---------------- aggregation, H=1 C=32 ----------------
__global__ __launch_bounds__(256) void agg_h1(const int* __restrict__ offs, const int* __restrict__ srcs,
                                              const float* __restrict__ h3, const float* __restrict__ als,
                                              const float* __restrict__ ald, const float* __restrict__ bias,
                                              float* __restrict__ out) {
    int wid = threadIdx.x >> 6, lane = threadIdx.x & 63;
    int n = blockIdx.x * 4 + wid;
    if (n >= N_NODES) return;
    int q = lane >> 3, cc = lane & 7;
    float ad = ald[n];
    int e0 = offs[n], e1 = offs[n + 1];
    float4 acc = make_float4(0.f, 0.f, 0.f, 0.f);
    float den = 0.f;
    for (int e = e0; e < e1; e += 8) {
        int ee = e + q;
        int idx = (ee < e1) ? ee : (e1 - 1);
        int s = srcs[idx];
        float w = __expf(lrelu(als[s] + ad));
        w = (ee < e1) ? w : 0.f;
        float4 hv = *reinterpret_cast<const float4*>(&h3[(long)s * 32 + cc * 4]);
        den += w;
        acc.x = fmaf(w, hv.x, acc.x);
        acc.y = fmaf(w, hv.y, acc.y);
        acc.z = fmaf(w, hv.z, acc.z);
        acc.w = fmaf(w, hv.w, acc.w);
    }
    acc.x += __shfl_xor(acc.x, 8);  acc.y += __shfl_xor(acc.y, 8);
    acc.z += __shfl_xor(acc.z, 8);  acc.w += __shfl_xor(acc.w, 8);
    den += __shfl_xor(den, 8);
    acc.x += __shfl_xor(acc.x, 16); acc.y += __shfl_xor(acc.y, 16);
    acc.z += __shfl_xor(acc.z, 16); acc.w += __shfl_xor(acc.w, 16);
    den += __shfl_xor(den, 16);
    acc.x += __shfl_xor(acc.x, 32); acc.y += __shfl_xor(acc.y, 32);
    acc.z += __shfl_xor(acc.z, 32); acc.w += __shfl_xor(acc.w, 32);
    den += __shfl_xor(den, 32);
    if (q == 0) {
        float4 b4 = *reinterpret_cast<const float4*>(&bias[cc * 4]);
        float inv = 1.f / den;
        float4 o;
        o.x = fmaf(acc.x, inv, b4.x);
        o.y = fmaf(acc.y, inv, b4.y);
        o.z = fmaf(acc.z, inv, b4.z);
        o.w = fmaf(acc.w, inv, b4.w);
        *reinterpret_cast<float4*>(&out[(long)n * 32 + cc * 4]) = o;
    }
}

extern "C" void kernel_launch(void* const* d_in, const int* in_sizes, int n_in,
                              void* d_out, int out_size, void* d_ws, size_t ws_size,
                              hipStream_t stream) {
    (void)in_sizes; (void)n_in; (void)out_size; (void)ws_size;
    const float* x   = (const float*)d_in[0];
    const int*   ei  = (const int*)d_in[1];
    const float* W1  = (const float*)d_in[2];
    const float* as1 = (const float*)d_in[3];
    const float* ad1 = (const float*)d_in[4];
    const float* b1  = (const float*)d_in[5];
    const float* W2  = (const float*)d_in[6];
    const float* as2 = (const float*)d_in[7];
    const float* ad2 = (const float*)d_in[8];
    const float* b2  = (const float*)d_in[9];
    const float* W3  = (const float*)d_in[10];
    const float* as3 = (const float*)d_in[11];
    const float* ad3 = (const float*)d_in[12];
    const float* b3  = (const float*)d_in[13];
    float* out = (float*)d_out;

    char* w = (char*)d_ws;
    auto alloc = [&](size_t bytes) {
        void* p = (void*)w;
        w += (bytes + 255) & ~(size_t)255;
        return p;
    };
    int*   cnt    = (int*)alloc((size_t)N_NODES * 4);
    int*   offs   = (int*)alloc((size_t)(N_NODES + 1) * 4);
    int*   bsum   = (int*)alloc(512 * 4);
    int*   cursor = (int*)alloc((size_t)N_NODES * 4);
    int*   srcs   = (int*)alloc((size_t)E_TOT * 4);
    float* h      = (float*)alloc((size_t)N_NODES * 64 * 4);
    float* g      = (float*)alloc((size_t)N_NODES * 64 * 4);
    float* als    = (float*)alloc((size_t)N_NODES * 4 * 4);
    float* ald    = (float*)alloc((size_t)N_NODES * 4 * 4);

    hipMemsetAsync(cnt, 0, (size_t)N_NODES * 4, stream);

    int gN = (N_NODES + 255) / 256;   // 391
    csr_count<<<NPART * PART_BLOCKS, 256, 0, stream>>>(ei, cnt);
    scan1<<<gN, 256, 0, stream>>>(cnt, offs, bsum);
    scan2<<<1, 512, 0, stream>>>(bsum, gN);
    scan3<<<gN, 256, 0, stream>>>(offs, bsum, cursor);
    csr_scatter<<<NPART * PART_BLOCKS, 256, 0, stream>>>(ei, cursor, srcs);

    int g64  = (N_NODES + 63) / 64;    // 1563
    int g128 = (N_NODES + 127) / 128;  // 782
    // layer 1: x[100000,128] @ W1[128,64], H=4
    gemm_al<128, 64, 4, 64><<<g64, 256, 0, stream>>>(x, W1, as1, ad1, h, als, ald);
    agg_h4<<<N_NODES / 4, 256, 0, stream>>>(offs, srcs, h, als, ald, b1, g, 1);
    // layer 2: g[100000,64] @ W2[64,64], H=4
    gemm_al<64, 64, 4, 64><<<g64, 256, 0, stream>>>(g, W2, as2, ad2, h, als, ald);
    agg_h4<<<N_NODES / 4, 256, 0, stream>>>(offs, srcs, h, als, ald, b2, g, 1);
    // layer 3: g[100000,64] @ W3[64,32], H=1 -> d_out
    gemm_al<64, 32, 1, 128><<<g128, 256, 0, stream>>>(g, W3, as3, ad3, h, als, ald);
    agg_h1<<<N_NODES / 4, 256, 0, stream>>>(offs, srcs, h, als, ald, b3, out);
}

// Round 7
// 515.715 us; speedup vs baseline: 1.6317x; 1.0052x over previous
//
#include <hip/hip_runtime.h>

#define N_NODES 100000
#define N_EDGES 1600000
#define E_TOT   (N_EDGES + N_NODES)
#define NPART   8
#define PART_SZ (N_NODES / NPART)   // 12500
#define PART_BLOCKS 256             // blocks per partition
#define CSR_BLOCKS (NPART * PART_BLOCKS)

static __device__ __forceinline__ float lrelu(float z) { return z > 0.f ? z : 0.2f * z; }

// ---------------- CSR count body (XCD-partitioned by dst range) ----------------
static __device__ __forceinline__ void count_body(int blk, const int* __restrict__ ei, int* __restrict__ cnt) {
    int part = blk & (NPART - 1);
    int lo = part * PART_SZ, hi = lo + PART_SZ;
    int stride = (CSR_BLOCKS / NPART) * 256;
    for (int t = (blk / NPART) * 256 + threadIdx.x; t < E_TOT; t += stride) {
        int d = (t < N_EDGES) ? ei[N_EDGES + t] : (t - N_EDGES);
        if (d >= lo && d < hi) atomicAdd(&cnt[d], 1);
    }
}

__global__ __launch_bounds__(256) void csr_scatter(const int* __restrict__ ei, int* __restrict__ cursor,
                                                   int* __restrict__ srcs) {
    int part = blockIdx.x & (NPART - 1);
    int lo = part * PART_SZ, hi = lo + PART_SZ;
    int stride = (gridDim.x / NPART) * 256;
    for (int t = (blockIdx.x / NPART) * 256 + threadIdx.x; t < E_TOT; t += stride) {
        int d = (t < N_EDGES) ? ei[N_EDGES + t] : (t - N_EDGES);
        if (d >= lo && d < hi) {
            int s = (t < N_EDGES) ? ei[t] : d;
            int pos = atomicAdd(&cursor[d], 1);
            srcs[pos] = s;
        }
    }
}

__global__ void scan1(const int* __restrict__ cnt, int* __restrict__ offs, int* __restrict__ bsum) {
    __shared__ int s[256];
    int t = threadIdx.x, i = blockIdx.x * 256 + t;
    int v = (i < N_NODES) ? cnt[i] : 0;
    s[t] = v; __syncthreads();
    for (int d = 1; d < 256; d <<= 1) {
        int a = (t >= d) ? s[t - d] : 0; __syncthreads();
        s[t] += a; __syncthreads();
    }
    if (i < N_NODES) offs[i] = s[t] - v;
    if (t == 255) bsum[blockIdx.x] = s[255];
}

__global__ void scan2(int* __restrict__ bsum, int nb) {
    __shared__ int s[512];
    int t = threadIdx.x;
    int v = (t < nb) ? bsum[t] : 0;
    s[t] = v; __syncthreads();
    for (int d = 1; d < 512; d <<= 1) {
        int a = (t >= d) ? s[t - d] : 0; __syncthreads();
        s[t] += a; __syncthreads();
    }
    if (t < nb) bsum[t] = s[t] - v;
}

__global__ void scan3(int* __restrict__ offs, const int* __restrict__ bsum, int* __restrict__ cursor) {
    int i = blockIdx.x * 256 + threadIdx.x;
    if (i < N_NODES) {
        int o = offs[i] + bsum[i >> 8];
        offs[i] = o;
        cursor[i] = o;
    }
    if (i == 0) offs[N_NODES] = E_TOT;
}

// ---------------- fused GEMM + attention logits body (wave-sliced, scalar W path) ----------------
// readfirstlane forces the W address chain into SGPRs -> s_load per k-row (round-6 win).
template <int IN, int OUT, int HEADS, int NPB>
static __device__ __forceinline__ void gemm_body(int blk, float* sx,
                                                 const float* __restrict__ x, const float* __restrict__ W,
                                                 const float* __restrict__ asrc, const float* __restrict__ adst,
                                                 float* __restrict__ h, float* __restrict__ als,
                                                 float* __restrict__ ald) {
    constexpr int SPLIT = OUT / 16;
    constexpr int STRIDE = IN + 1;
    constexpr int F4PT = NPB * (IN / 4) / 256;
    int t = threadIdx.x;
    long base = (long)blk * NPB;

#pragma unroll
    for (int p = 0; p < F4PT; ++p) {
        int e = p * 256 + t;
        int row = e / (IN / 4);
        int c4 = e % (IN / 4);
        long gr = base + row;
        if (gr >= N_NODES) gr = N_NODES - 1;
        float4 v = *reinterpret_cast<const float4*>(&x[gr * IN + c4 * 4]);
        float* d = &sx[row * STRIDE + c4 * 4];
        d[0] = v.x; d[1] = v.y; d[2] = v.z; d[3] = v.w;
    }
    __syncthreads();

    int w = t >> 6, lane = t & 63;
    int s = __builtin_amdgcn_readfirstlane(w % SPLIT);
    int grp = __builtin_amdgcn_readfirstlane(w / SPLIT);
    int r = grp * 64 + lane;
    long n = base + r;

    float acc[16];
#pragma unroll
    for (int j = 0; j < 16; ++j) acc[j] = 0.f;

    const float* Ws = W + s * 16;
#pragma unroll 8
    for (int k = 0; k < IN; ++k) {
        float xv = sx[r * STRIDE + k];
        const float* Wr = Ws + k * OUT;
#pragma unroll
        for (int j = 0; j < 16; ++j) acc[j] = fmaf(xv, Wr[j], acc[j]);
    }

    if (n < N_NODES) {
#pragma unroll
        for (int j = 0; j < 16; j += 4) {
            *reinterpret_cast<float4*>(&h[n * OUT + s * 16 + j]) =
                make_float4(acc[j], acc[j + 1], acc[j + 2], acc[j + 3]);
        }
    }

    float ps = 0.f, pd = 0.f;
#pragma unroll
    for (int j = 0; j < 16; ++j) {
        ps = fmaf(acc[j], asrc[s * 16 + j], ps);
        pd = fmaf(acc[j], adst[s * 16 + j], pd);
    }
    if (HEADS == SPLIT) {
        if (n < N_NODES) {
            als[n * HEADS + s] = ps;
            ald[n * HEADS + s] = pd;
        }
    } else {
        __syncthreads();
        sx[r * 2 + s] = ps;
        sx[NPB * 2 + r * 2 + s] = pd;
        __syncthreads();
        if (t < NPB) {
            long nn = base + t;
            if (nn < N_NODES) {
                als[nn] = sx[t * 2] + sx[t * 2 + 1];
                ald[nn] = sx[NPB * 2 + t * 2] + sx[NPB * 2 + t * 2 + 1];
            }
        }
    }
}

template <int IN, int OUT, int HEADS, int NPB>
__global__ __launch_bounds__(256) void gemm_al(const float* __restrict__ x, const float* __restrict__ W,
                                               const float* __restrict__ asrc, const float* __restrict__ adst,
                                               float* __restrict__ h, float* __restrict__ als,
                                               float* __restrict__ ald) {
    __shared__ float sx[NPB * (IN + 1)];
    gemm_body<IN, OUT, HEADS, NPB>(blockIdx.x, sx, x, W, asrc, adst, h, als, ald);
}

// ---------------- fused csr_count + layer-1 GEMM ----------------
// gemm1 is independent of the CSR chain; a single stream serializes them.
// Block-split fusion runs them concurrently: blocks [0,2048) = count
// (partition = blk&7 preserved), blocks [2048, 2048+1563) = gemm L1.
__global__ __launch_bounds__(256) void fused_count_gemm1(const int* __restrict__ ei, int* __restrict__ cnt,
                                                         const float* __restrict__ x, const float* __restrict__ W,
                                                         const float* __restrict__ asrc, const float* __restrict__ adst,
                                                         float* __restrict__ h, float* __restrict__ als,
                                                         float* __restrict__ ald) {
    __shared__ float sx[64 * 129];
    if (blockIdx.x < CSR_BLOCKS) {
        count_body(blockIdx.x, ei, cnt);
    } else {
        gemm_body<128, 64, 4, 64>(blockIdx.x - CSR_BLOCKS, sx, x, W, asrc, adst, h, als, ald);
    }
}

// ---------------- aggregation, H=4 C=16 (software-pipelined) ----------------
// wave/node; q=lane>>4 = edge slot (4 edges/batch), cc=lane&15 = float4 slice.
// 1-deep rotate: batch B's srcs/als/h loads issue while batch A computes, so
// the srcs->h serial dependency's latency hides behind a full loop body.
__global__ __launch_bounds__(256) void agg_h4(const int* __restrict__ offs, const int* __restrict__ srcs,
                                              const float* __restrict__ h, const float* __restrict__ als,
                                              const float* __restrict__ ald, const float* __restrict__ bias,
                                              float* __restrict__ g, int do_relu) {
    int wid = threadIdx.x >> 6, lane = threadIdx.x & 63;
    int n = blockIdx.x * 4 + wid;
    if (n >= N_NODES) return;
    int q = lane >> 4, cc = lane & 15;
    int hd = cc >> 2;
    float ad = ald[n * 4 + hd];
    int e0 = offs[n], e1 = offs[n + 1];   // wave-uniform; e1>e0 (self-loop)
    float4 acc = make_float4(0.f, 0.f, 0.f, 0.f);
    float den = 0.f;

    int idxA = e0 + q; if (idxA >= e1) idxA = e1 - 1;
    int sA = srcs[idxA];
    float alA = als[sA * 4 + hd];
    float4 hvA = *reinterpret_cast<const float4*>(&h[(long)sA * 64 + cc * 4]);
    bool mA = (e0 + q) < e1;

    for (int e = e0; e < e1; e += 4) {
        int eB = e + 4;
        int sB = sA; float alB = alA; float4 hvB = hvA; bool mB = mA;
        if (eB < e1) {                    // wave-uniform branch
            int idxB = eB + q; if (idxB >= e1) idxB = e1 - 1;
            sB = srcs[idxB];
            alB = als[sB * 4 + hd];
            hvB = *reinterpret_cast<const float4*>(&h[(long)sB * 64 + cc * 4]);
            mB = (eB + q) < e1;
        }
        float w = mA ? __expf(lrelu(alA + ad)) : 0.f;
        den += w;
        acc.x = fmaf(w, hvA.x, acc.x);
        acc.y = fmaf(w, hvA.y, acc.y);
        acc.z = fmaf(w, hvA.z, acc.z);
        acc.w = fmaf(w, hvA.w, acc.w);
        sA = sB; alA = alB; hvA = hvB; mA = mB;
    }

    acc.x += __shfl_xor(acc.x, 16); acc.y += __shfl_xor(acc.y, 16);
    acc.z += __shfl_xor(acc.z, 16); acc.w += __shfl_xor(acc.w, 16);
    den += __shfl_xor(den, 16);
    acc.x += __shfl_xor(acc.x, 32); acc.y += __shfl_xor(acc.y, 32);
    acc.z += __shfl_xor(acc.z, 32); acc.w += __shfl_xor(acc.w, 32);
    den += __shfl_xor(den, 32);
    if (q == 0) {
        float4 b4 = *reinterpret_cast<const float4*>(&bias[cc * 4]);
        float inv = 1.f / den;
        float4 o;
        o.x = fmaf(acc.x, inv, b4.x);
        o.y = fmaf(acc.y, inv, b4.y);
        o.z = fmaf(acc.z, inv, b4.z);
        o.w = fmaf(acc.w, inv, b4.w);
        if (do_relu) {
            o.x = fmaxf(o.x, 0.f); o.y = fmaxf(o.y, 0.f);
            o.z = fmaxf(o.z, 0.f); o.w = fmaxf(o.w, 0.f);
        }
        *reinterpret_cast<float4*>(&g[(long)n * 64 + cc * 4]) = o;
    }
}

// ---------------- aggregation, H=1 C=32 (software-pipelined) ----------------
__global__ __launch_bounds__(256) void agg_h1(const int* __restrict__ offs, const int* __restrict__ srcs,
                                              const float* __restrict__ h3, const float* __restrict__ als,
                                              const float* __restrict__ ald, const float* __restrict__ bias,
                                              float* __restrict__ out) {
    int wid = threadIdx.x >> 6, lane = threadIdx.x & 63;
    int n = blockIdx.x * 4 + wid;
    if (n >= N_NODES) return;
    int q = lane >> 3, cc = lane & 7;
    float ad = ald[n];
    int e0 = offs[n], e1 = offs[n + 1];
    float4 acc = make_float4(0.f, 0.f, 0.f, 0.f);
    float den = 0.f;

    int idxA = e0 + q; if (idxA >= e1) idxA = e1 - 1;
    int sA = srcs[idxA];
    float alA = als[sA];
    float4 hvA = *reinterpret_cast<const float4*>(&h3[(long)sA * 32 + cc * 4]);
    bool mA = (e0 + q) < e1;

    for (int e = e0; e < e1; e += 8) {
        int eB = e + 8;
        int sB = sA; float alB = alA; float4 hvB = hvA; bool mB = mA;
        if (eB < e1) {
            int idxB = eB + q; if (idxB >= e1) idxB = e1 - 1;
            sB = srcs[idxB];
            alB = als[sB];
            hvB = *reinterpret_cast<const float4*>(&h3[(long)sB * 32 + cc * 4]);
            mB = (eB + q) < e1;
        }
        float w = mA ? __expf(lrelu(alA + ad)) : 0.f;
        den += w;
        acc.x = fmaf(w, hvA.x, acc.x);
        acc.y = fmaf(w, hvA.y, acc.y);
        acc.z = fmaf(w, hvA.z, acc.z);
        acc.w = fmaf(w, hvA.w, acc.w);
        sA = sB; alA = alB; hvA = hvB; mA = mB;
    }

    acc.x += __shfl_xor(acc.x, 8);  acc.y += __shfl_xor(acc.y, 8);
    acc.z += __shfl_xor(acc.z, 8);  acc.w += __shfl_xor(acc.w, 8);
    den += __shfl_xor(den, 8);
    acc.x += __shfl_xor(acc.x, 16); acc.y += __shfl_xor(acc.y, 16);
    acc.z += __shfl_xor(acc.z, 16); acc.w += __shfl_xor(acc.w, 16);
    den += __shfl_xor(den, 16);
    acc.x += __shfl_xor(acc.x, 32); acc.y += __shfl_xor(acc.y, 32);
    acc.z += __shfl_xor(acc.z, 32); acc.w += __shfl_xor(acc.w, 32);
    den += __shfl_xor(den, 32);
    if (q == 0) {
        float4 b4 = *reinterpret_cast<const float4*>(&bias[cc * 4]);
        float inv = 1.f / den;
        float4 o;
        o.x = fmaf(acc.x, inv, b4.x);
        o.y = fmaf(acc.y, inv, b4.y);
        o.z = fmaf(acc.z, inv, b4.z);
        o.w = fmaf(acc.w, inv, b4.w);
        *reinterpret_cast<float4*>(&out[(long)n * 32 + cc * 4]) = o;
    }
}

extern "C" void kernel_launch(void* const* d_in, const int* in_sizes, int n_in,
                              void* d_out, int out_size, void* d_ws, size_t ws_size,
                              hipStream_t stream) {
    (void)in_sizes; (void)n_in; (void)out_size; (void)ws_size;
    const float* x   = (const float*)d_in[0];
    const int*   ei  = (const int*)d_in[1];
    const float* W1  = (const float*)d_in[2];
    const float* as1 = (const float*)d_in[3];
    const float* ad1 = (const float*)d_in[4];
    const float* b1  = (const float*)d_in[5];
    const float* W2  = (const float*)d_in[6];
    const float* as2 = (const float*)d_in[7];
    const float* ad2 = (const float*)d_in[8];
    const float* b2  = (const float*)d_in[9];
    const float* W3  = (const float*)d_in[10];
    const float* as3 = (const float*)d_in[11];
    const float* ad3 = (const float*)d_in[12];
    const float* b3  = (const float*)d_in[13];
    float* out = (float*)d_out;

    char* w = (char*)d_ws;
    auto alloc = [&](size_t bytes) {
        void* p = (void*)w;
        w += (bytes + 255) & ~(size_t)255;
        return p;
    };
    int*   cnt    = (int*)alloc((size_t)N_NODES * 4);
    int*   offs   = (int*)alloc((size_t)(N_NODES + 1) * 4);
    int*   bsum   = (int*)alloc(512 * 4);
    int*   cursor = (int*)alloc((size_t)N_NODES * 4);
    int*   srcs   = (int*)alloc((size_t)E_TOT * 4);
    float* h      = (float*)alloc((size_t)N_NODES * 64 * 4);
    float* g      = (float*)alloc((size_t)N_NODES * 64 * 4);
    float* als    = (float*)alloc((size_t)N_NODES * 4 * 4);
    float* ald    = (float*)alloc((size_t)N_NODES * 4 * 4);

    hipMemsetAsync(cnt, 0, (size_t)N_NODES * 4, stream);

    int gN = (N_NODES + 255) / 256;    // 391
    int g64  = (N_NODES + 63) / 64;    // 1563
    int g128 = (N_NODES + 127) / 128;  // 782

    // csr_count runs fused with layer-1 gemm (independent work, one dispatch)
    fused_count_gemm1<<<CSR_BLOCKS + g64, 256, 0, stream>>>(ei, cnt, x, W1, as1, ad1, h, als, ald);
    scan1<<<gN, 256, 0, stream>>>(cnt, offs, bsum);
    scan2<<<1, 512, 0, stream>>>(bsum, gN);
    scan3<<<gN, 256, 0, stream>>>(offs, bsum, cursor);
    csr_scatter<<<CSR_BLOCKS, 256, 0, stream>>>(ei, cursor, srcs);

    // layer 1 aggregation
    agg_h4<<<N_NODES / 4, 256, 0, stream>>>(offs, srcs, h, als, ald, b1, g, 1);
    // layer 2: g[100000,64] @ W2[64,64], H=4
    gemm_al<64, 64, 4, 64><<<g64, 256, 0, stream>>>(g, W2, as2, ad2, h, als, ald);
    agg_h4<<<N_NODES / 4, 256, 0, stream>>>(offs, srcs, h, als, ald, b2, g, 1);
    // layer 3: g[100000,64] @ W3[64,32], H=1 -> d_out
    gemm_al<64, 32, 1, 128><<<g128, 256, 0, stream>>>(g, W3, as3, ad3, h, als, ald);
    agg_h1<<<N_NODES / 4, 256, 0, stream>>>(offs, srcs, h, als, ald, b3, out);
}

// Round 8
// 450.215 us; speedup vs baseline: 1.8690x; 1.1455x over previous
//
#include <hip/hip_runtime.h>

#define N_NODES 100000
#define N_EDGES 1600000
#define E_TOT   (N_EDGES + N_NODES)
#define NPART   8
#define PART_SZ (N_NODES / NPART)   // 12500
#define PART_BLOCKS 256             // blocks per partition
#define CSR_BLOCKS (NPART * PART_BLOCKS)
#define CAP 48                      // bucket capacity; degree ~ Poisson(16), P(>=48) ~ 1e-9

static __device__ __forceinline__ float lrelu(float z) { return z > 0.f ? z : 0.2f * z; }

// ---------------- bucket scatter (replaces count+scan+scatter) ----------------
// Fixed-capacity buckets: slot = atomicAdd(cnt[d]), srcs[d*CAP+slot] = s.
// Partitioned by dst range (partition = blk&7 -> XCD round-robin): each
// partition's cnt slice (50 KB) + bucket region (2.4 MB) stay resident in ONE
// XCD's L2 -> atomics and stores never ping-pong (round-1/2 lesson). NOT fused
// with gemm1: round-7 showed streaming reads evict the atomic lines (78 MB
// writeback pathology).
__global__ __launch_bounds__(256) void bucket_scatter(const int* __restrict__ ei, int* __restrict__ cnt,
                                                      int* __restrict__ srcs) {
    int part = blockIdx.x & (NPART - 1);
    int lo = part * PART_SZ, hi = lo + PART_SZ;
    int stride = (CSR_BLOCKS / NPART) * 256;
    for (int t = (blockIdx.x / NPART) * 256 + threadIdx.x; t < E_TOT; t += stride) {
        int d = (t < N_EDGES) ? ei[N_EDGES + t] : (t - N_EDGES);
        if (d >= lo && d < hi) {
            int s = (t < N_EDGES) ? ei[t] : d;
            int slot = atomicAdd(&cnt[d], 1);
            if (slot < CAP) srcs[d * CAP + slot] = s;
        }
    }
}

// ---------------- fused GEMM + attention logits (wave-sliced, scalar W path) ----------------
// readfirstlane forces the W address chain into SGPRs -> s_load per k-row (round-6 win).
template <int IN, int OUT, int HEADS, int NPB>
__global__ __launch_bounds__(256) void gemm_al(const float* __restrict__ x, const float* __restrict__ W,
                                               const float* __restrict__ asrc, const float* __restrict__ adst,
                                               float* __restrict__ h, float* __restrict__ als,
                                               float* __restrict__ ald) {
    constexpr int SPLIT = OUT / 16;
    constexpr int STRIDE = IN + 1;
    constexpr int F4PT = NPB * (IN / 4) / 256;
    __shared__ float sx[NPB * STRIDE];
    int t = threadIdx.x;
    long base = (long)blockIdx.x * NPB;

#pragma unroll
    for (int p = 0; p < F4PT; ++p) {
        int e = p * 256 + t;
        int row = e / (IN / 4);
        int c4 = e % (IN / 4);
        long gr = base + row;
        if (gr >= N_NODES) gr = N_NODES - 1;
        float4 v = *reinterpret_cast<const float4*>(&x[gr * IN + c4 * 4]);
        float* d = &sx[row * STRIDE + c4 * 4];
        d[0] = v.x; d[1] = v.y; d[2] = v.z; d[3] = v.w;
    }
    __syncthreads();

    int w = t >> 6, lane = t & 63;
    int s = __builtin_amdgcn_readfirstlane(w % SPLIT);
    int grp = __builtin_amdgcn_readfirstlane(w / SPLIT);
    int r = grp * 64 + lane;
    long n = base + r;

    float acc[16];
#pragma unroll
    for (int j = 0; j < 16; ++j) acc[j] = 0.f;

    const float* Ws = W + s * 16;
#pragma unroll 8
    for (int k = 0; k < IN; ++k) {
        float xv = sx[r * STRIDE + k];
        const float* Wr = Ws + k * OUT;
#pragma unroll
        for (int j = 0; j < 16; ++j) acc[j] = fmaf(xv, Wr[j], acc[j]);
    }

    if (n < N_NODES) {
#pragma unroll
        for (int j = 0; j < 16; j += 4) {
            *reinterpret_cast<float4*>(&h[n * OUT + s * 16 + j]) =
                make_float4(acc[j], acc[j + 1], acc[j + 2], acc[j + 3]);
        }
    }

    float ps = 0.f, pd = 0.f;
#pragma unroll
    for (int j = 0; j < 16; ++j) {
        ps = fmaf(acc[j], asrc[s * 16 + j], ps);
        pd = fmaf(acc[j], adst[s * 16 + j], pd);
    }
    if (HEADS == SPLIT) {
        if (n < N_NODES) {
            als[n * HEADS + s] = ps;
            ald[n * HEADS + s] = pd;
        }
    } else {
        __syncthreads();
        sx[r * 2 + s] = ps;
        sx[NPB * 2 + r * 2 + s] = pd;
        __syncthreads();
        if (t < NPB) {
            long nn = base + t;
            if (nn < N_NODES) {
                als[nn] = sx[t * 2] + sx[t * 2 + 1];
                ald[nn] = sx[NPB * 2 + t * 2] + sx[NPB * 2 + t * 2 + 1];
            }
        }
    }
}

// XCD-aligned node mapping for agg: XCD k (blockIdx&7) processes dst range
// [k*12500, (k+1)*12500) -> cnt/srcs lines written by partition k's scatter
// are still warm in that XCD's L2.
static __device__ __forceinline__ int agg_node(int blk, int wid) {
    return (blk & 7) * PART_SZ + (blk >> 3) * 4 + wid;
}

// ---------------- aggregation, H=4 C=16 (software-pipelined) ----------------
// wave/node; q=lane>>4 = edge slot (4 edges/batch), cc=lane&15 = float4 slice.
__global__ __launch_bounds__(256) void agg_h4(const int* __restrict__ cnt, const int* __restrict__ srcs,
                                              const float* __restrict__ h, const float* __restrict__ als,
                                              const float* __restrict__ ald, const float* __restrict__ bias,
                                              float* __restrict__ g, int do_relu) {
    int wid = threadIdx.x >> 6, lane = threadIdx.x & 63;
    int n = agg_node(blockIdx.x, wid);
    if (n >= N_NODES) return;
    int q = lane >> 4, cc = lane & 15;
    int hd = cc >> 2;
    float ad = ald[n * 4 + hd];
    int deg = cnt[n]; if (deg > CAP) deg = CAP;   // deg >= 1 (self-loop)
    int e0 = n * CAP, e1 = e0 + deg;
    float4 acc = make_float4(0.f, 0.f, 0.f, 0.f);
    float den = 0.f;

    int idxA = e0 + q; if (idxA >= e1) idxA = e1 - 1;
    int sA = srcs[idxA];
    float alA = als[sA * 4 + hd];
    float4 hvA = *reinterpret_cast<const float4*>(&h[(long)sA * 64 + cc * 4]);
    bool mA = (e0 + q) < e1;

    for (int e = e0; e < e1; e += 4) {
        int eB = e + 4;
        int sB = sA; float alB = alA; float4 hvB = hvA; bool mB = mA;
        if (eB < e1) {                    // wave-uniform branch
            int idxB = eB + q; if (idxB >= e1) idxB = e1 - 1;
            sB = srcs[idxB];
            alB = als[sB * 4 + hd];
            hvB = *reinterpret_cast<const float4*>(&h[(long)sB * 64 + cc * 4]);
            mB = (eB + q) < e1;
        }
        float w = mA ? __expf(lrelu(alA + ad)) : 0.f;
        den += w;
        acc.x = fmaf(w, hvA.x, acc.x);
        acc.y = fmaf(w, hvA.y, acc.y);
        acc.z = fmaf(w, hvA.z, acc.z);
        acc.w = fmaf(w, hvA.w, acc.w);
        sA = sB; alA = alB; hvA = hvB; mA = mB;
    }

    acc.x += __shfl_xor(acc.x, 16); acc.y += __shfl_xor(acc.y, 16);
    acc.z += __shfl_xor(acc.z, 16); acc.w += __shfl_xor(acc.w, 16);
    den += __shfl_xor(den, 16);
    acc.x += __shfl_xor(acc.x, 32); acc.y += __shfl_xor(acc.y, 32);
    acc.z += __shfl_xor(acc.z, 32); acc.w += __shfl_xor(acc.w, 32);
    den += __shfl_xor(den, 32);
    if (q == 0) {
        float4 b4 = *reinterpret_cast<const float4*>(&bias[cc * 4]);
        float inv = 1.f / den;
        float4 o;
        o.x = fmaf(acc.x, inv, b4.x);
        o.y = fmaf(acc.y, inv, b4.y);
        o.z = fmaf(acc.z, inv, b4.z);
        o.w = fmaf(acc.w, inv, b4.w);
        if (do_relu) {
            o.x = fmaxf(o.x, 0.f); o.y = fmaxf(o.y, 0.f);
            o.z = fmaxf(o.z, 0.f); o.w = fmaxf(o.w, 0.f);
        }
        *reinterpret_cast<float4*>(&g[(long)n * 64 + cc * 4]) = o;
    }
}

// ---------------- aggregation, H=1 C=32 (software-pipelined) ----------------
__global__ __launch_bounds__(256) void agg_h1(const int* __restrict__ cnt, const int* __restrict__ srcs,
                                              const float* __restrict__ h3, const float* __restrict__ als,
                                              const float* __restrict__ ald, const float* __restrict__ bias,
                                              float* __restrict__ out) {
    int wid = threadIdx.x >> 6, lane = threadIdx.x & 63;
    int n = agg_node(blockIdx.x, wid);
    if (n >= N_NODES) return;
    int q = lane >> 3, cc = lane & 7;
    float ad = ald[n];
    int deg = cnt[n]; if (deg > CAP) deg = CAP;
    int e0 = n * CAP, e1 = e0 + deg;
    float4 acc = make_float4(0.f, 0.f, 0.f, 0.f);
    float den = 0.f;

    int idxA = e0 + q; if (idxA >= e1) idxA = e1 - 1;
    int sA = srcs[idxA];
    float alA = als[sA];
    float4 hvA = *reinterpret_cast<const float4*>(&h3[(long)sA * 32 + cc * 4]);
    bool mA = (e0 + q) < e1;

    for (int e = e0; e < e1; e += 8) {
        int eB = e + 8;
        int sB = sA; float alB = alA; float4 hvB = hvA; bool mB = mA;
        if (eB < e1) {
            int idxB = eB + q; if (idxB >= e1) idxB = e1 - 1;
            sB = srcs[idxB];
            alB = als[sB];
            hvB = *reinterpret_cast<const float4*>(&h3[(long)sB * 32 + cc * 4]);
            mB = (eB + q) < e1;
        }
        float w = mA ? __expf(lrelu(alA + ad)) : 0.f;
        den += w;
        acc.x = fmaf(w, hvA.x, acc.x);
        acc.y = fmaf(w, hvA.y, acc.y);
        acc.z = fmaf(w, hvA.z, acc.z);
        acc.w = fmaf(w, hvA.w, acc.w);
        sA = sB; alA = alB; hvA = hvB; mA = mB;
    }

    acc.x += __shfl_xor(acc.x, 8);  acc.y += __shfl_xor(acc.y, 8);
    acc.z += __shfl_xor(acc.z, 8);  acc.w += __shfl_xor(acc.w, 8);
    den += __shfl_xor(den, 8);
    acc.x += __shfl_xor(acc.x, 16); acc.y += __shfl_xor(acc.y, 16);
    acc.z += __shfl_xor(acc.z, 16); acc.w += __shfl_xor(acc.w, 16);
    den += __shfl_xor(den, 16);
    acc.x += __shfl_xor(acc.x, 32); acc.y += __shfl_xor(acc.y, 32);
    acc.z += __shfl_xor(acc.z, 32); acc.w += __shfl_xor(acc.w, 32);
    den += __shfl_xor(den, 32);
    if (q == 0) {
        float4 b4 = *reinterpret_cast<const float4*>(&bias[cc * 4]);
        float inv = 1.f / den;
        float4 o;
        o.x = fmaf(acc.x, inv, b4.x);
        o.y = fmaf(acc.y, inv, b4.y);
        o.z = fmaf(acc.z, inv, b4.z);
        o.w = fmaf(acc.w, inv, b4.w);
        *reinterpret_cast<float4*>(&out[(long)n * 32 + cc * 4]) = o;
    }
}

extern "C" void kernel_launch(void* const* d_in, const int* in_sizes, int n_in,
                              void* d_out, int out_size, void* d_ws, size_t ws_size,
                              hipStream_t stream) {
    (void)in_sizes; (void)n_in; (void)out_size; (void)ws_size;
    const float* x   = (const float*)d_in[0];
    const int*   ei  = (const int*)d_in[1];
    const float* W1  = (const float*)d_in[2];
    const float* as1 = (const float*)d_in[3];
    const float* ad1 = (const float*)d_in[4];
    const float* b1  = (const float*)d_in[5];
    const float* W2  = (const float*)d_in[6];
    const float* as2 = (const float*)d_in[7];
    const float* ad2 = (const float*)d_in[8];
    const float* b2  = (const float*)d_in[9];
    const float* W3  = (const float*)d_in[10];
    const float* as3 = (const float*)d_in[11];
    const float* ad3 = (const float*)d_in[12];
    const float* b3  = (const float*)d_in[13];
    float* out = (float*)d_out;

    char* w = (char*)d_ws;
    auto alloc = [&](size_t bytes) {
        void* p = (void*)w;
        w += (bytes + 255) & ~(size_t)255;
        return p;
    };
    int*   cnt  = (int*)alloc((size_t)N_NODES * 4);
    int*   srcs = (int*)alloc((size_t)N_NODES * CAP * 4);   // 19.2 MB
    float* h    = (float*)alloc((size_t)N_NODES * 64 * 4);
    float* g    = (float*)alloc((size_t)N_NODES * 64 * 4);
    float* als  = (float*)alloc((size_t)N_NODES * 4 * 4);
    float* ald  = (float*)alloc((size_t)N_NODES * 4 * 4);

    hipMemsetAsync(cnt, 0, (size_t)N_NODES * 4, stream);

    int g64  = (N_NODES + 63) / 64;    // 1563
    int g128 = (N_NODES + 127) / 128;  // 782
    int gAgg = ((N_NODES + 3) / 4 + 7) & ~7;   // 25000 -> round to mult of 8

    bucket_scatter<<<CSR_BLOCKS, 256, 0, stream>>>(ei, cnt, srcs);

    // layer 1: x[100000,128] @ W1[128,64], H=4
    gemm_al<128, 64, 4, 64><<<g64, 256, 0, stream>>>(x, W1, as1, ad1, h, als, ald);
    agg_h4<<<gAgg, 256, 0, stream>>>(cnt, srcs, h, als, ald, b1, g, 1);
    // layer 2: g[100000,64] @ W2[64,64], H=4
    gemm_al<64, 64, 4, 64><<<g64, 256, 0, stream>>>(g, W2, as2, ad2, h, als, ald);
    agg_h4<<<gAgg, 256, 0, stream>>>(cnt, srcs, h, als, ald, b2, g, 1);
    // layer 3: g[100000,64] @ W3[64,32], H=1 -> d_out
    gemm_al<64, 32, 1, 128><<<g128, 256, 0, stream>>>(g, W3, as3, ad3, h, als, ald);
    agg_h1<<<gAgg, 256, 0, stream>>>(cnt, srcs, h, als, ald, b3, out);
}

// Round 9
// 420.330 us; speedup vs baseline: 2.0019x; 1.0711x over previous
//
#include <hip/hip_runtime.h>

#define N_NODES 100000
#define N_EDGES 1600000
#define E_TOT   (N_EDGES + N_NODES)
#define NPART   8
#define PART_SZ (N_NODES / NPART)   // 12500
#define PART_BLOCKS 256             // blocks per partition
#define CSR_BLOCKS (NPART * PART_BLOCKS)
#define CAP 48                      // bucket capacity; degree ~ Poisson(16), P(>=48) ~ 1e-9

static __device__ __forceinline__ float lrelu(float z) { return z > 0.f ? z : 0.2f * z; }

// bf16 round-to-nearest-even pack / unpack (values are finite, no NaN handling)
static __device__ __forceinline__ unsigned short f2bf(float f) {
    unsigned u = __float_as_uint(f);
    u += 0x7fffu + ((u >> 16) & 1u);
    return (unsigned short)(u >> 16);
}
static __device__ __forceinline__ float bf_lo(unsigned v) { return __uint_as_float(v << 16); }
static __device__ __forceinline__ float bf_hi(unsigned v) { return __uint_as_float(v & 0xffff0000u); }

// ---------------- bucket scatter (XCD-partitioned by dst range) ----------------
__global__ __launch_bounds__(256) void bucket_scatter(const int* __restrict__ ei, int* __restrict__ cnt,
                                                      int* __restrict__ srcs) {
    int part = blockIdx.x & (NPART - 1);
    int lo = part * PART_SZ, hi = lo + PART_SZ;
    int stride = (CSR_BLOCKS / NPART) * 256;
    for (int t = (blockIdx.x / NPART) * 256 + threadIdx.x; t < E_TOT; t += stride) {
        int d = (t < N_EDGES) ? ei[N_EDGES + t] : (t - N_EDGES);
        if (d >= lo && d < hi) {
            int s = (t < N_EDGES) ? ei[t] : d;
            int slot = atomicAdd(&cnt[d], 1);
            if (slot < CAP) srcs[d * CAP + slot] = s;
        }
    }
}

// ---------------- fused GEMM + attention logits (wave-sliced, scalar W path) ----------------
// readfirstlane forces the W address chain into SGPRs -> s_load per k-row (round-6 win).
// h is written as bf16 (RNE): halves the downstream gather traffic, which is the
// bottleneck (round-8: agg pinned at ~3.3 TB/s beyond-L2 fabric BW). als/ald stay
// fp32 from the fp32 accumulators.
template <int IN, int OUT, int HEADS, int NPB>
__global__ __launch_bounds__(256) void gemm_al(const float* __restrict__ x, const float* __restrict__ W,
                                               const float* __restrict__ asrc, const float* __restrict__ adst,
                                               unsigned short* __restrict__ h, float* __restrict__ als,
                                               float* __restrict__ ald) {
    constexpr int SPLIT = OUT / 16;
    constexpr int STRIDE = IN + 1;
    constexpr int F4PT = NPB * (IN / 4) / 256;
    __shared__ float sx[NPB * STRIDE];
    int t = threadIdx.x;
    long base = (long)blockIdx.x * NPB;

#pragma unroll
    for (int p = 0; p < F4PT; ++p) {
        int e = p * 256 + t;
        int row = e / (IN / 4);
        int c4 = e % (IN / 4);
        long gr = base + row;
        if (gr >= N_NODES) gr = N_NODES - 1;
        float4 v = *reinterpret_cast<const float4*>(&x[gr * IN + c4 * 4]);
        float* d = &sx[row * STRIDE + c4 * 4];
        d[0] = v.x; d[1] = v.y; d[2] = v.z; d[3] = v.w;
    }
    __syncthreads();

    int w = t >> 6, lane = t & 63;
    int s = __builtin_amdgcn_readfirstlane(w % SPLIT);
    int grp = __builtin_amdgcn_readfirstlane(w / SPLIT);
    int r = grp * 64 + lane;
    long n = base + r;

    float acc[16];
#pragma unroll
    for (int j = 0; j < 16; ++j) acc[j] = 0.f;

    const float* Ws = W + s * 16;
#pragma unroll 8
    for (int k = 0; k < IN; ++k) {
        float xv = sx[r * STRIDE + k];
        const float* Wr = Ws + k * OUT;
#pragma unroll
        for (int j = 0; j < 16; ++j) acc[j] = fmaf(xv, Wr[j], acc[j]);
    }

    if (n < N_NODES) {
#pragma unroll
        for (int j = 0; j < 16; j += 4) {
            ushort4 o;
            o.x = f2bf(acc[j]); o.y = f2bf(acc[j + 1]);
            o.z = f2bf(acc[j + 2]); o.w = f2bf(acc[j + 3]);
            *reinterpret_cast<ushort4*>(&h[n * OUT + s * 16 + j]) = o;
        }
    }

    float ps = 0.f, pd = 0.f;
#pragma unroll
    for (int j = 0; j < 16; ++j) {
        ps = fmaf(acc[j], asrc[s * 16 + j], ps);
        pd = fmaf(acc[j], adst[s * 16 + j], pd);
    }
    if (HEADS == SPLIT) {
        if (n < N_NODES) {
            als[n * HEADS + s] = ps;
            ald[n * HEADS + s] = pd;
        }
    } else {
        __syncthreads();
        sx[r * 2 + s] = ps;
        sx[NPB * 2 + r * 2 + s] = pd;
        __syncthreads();
        if (t < NPB) {
            long nn = base + t;
            if (nn < N_NODES) {
                als[nn] = sx[t * 2] + sx[t * 2 + 1];
                ald[nn] = sx[NPB * 2 + t * 2] + sx[NPB * 2 + t * 2 + 1];
            }
        }
    }
}

// XCD-aligned node mapping for agg: XCD k (blockIdx&7) processes dst range k.
static __device__ __forceinline__ int agg_node(int blk, int wid) {
    return (blk & 7) * PART_SZ + (blk >> 3) * 4 + wid;
}

// ---------------- aggregation, H=4 C=16, bf16 payload ----------------
// wave/node; q=lane>>4 = edge slot (4 edges/batch), cc=lane&15 = uint2 slice
// (16 lanes x 8 B = full 64-ch bf16 row). Software-pipelined 1-deep.
__global__ __launch_bounds__(256) void agg_h4(const int* __restrict__ cnt, const int* __restrict__ srcs,
                                              const unsigned short* __restrict__ h, const float* __restrict__ als,
                                              const float* __restrict__ ald, const float* __restrict__ bias,
                                              float* __restrict__ g, int do_relu) {
    const uint2* hrow = reinterpret_cast<const uint2*>(h);   // 16 uint2 per 64-ch row
    int wid = threadIdx.x >> 6, lane = threadIdx.x & 63;
    int n = agg_node(blockIdx.x, wid);
    if (n >= N_NODES) return;
    int q = lane >> 4, cc = lane & 15;
    int hd = cc >> 2;
    float ad = ald[n * 4 + hd];
    int deg = cnt[n]; if (deg > CAP) deg = CAP;   // deg >= 1 (self-loop)
    int e0 = n * CAP, e1 = e0 + deg;
    float4 acc = make_float4(0.f, 0.f, 0.f, 0.f);
    float den = 0.f;

    int idxA = e0 + q; if (idxA >= e1) idxA = e1 - 1;
    int sA = srcs[idxA];
    float alA = als[sA * 4 + hd];
    uint2 hvA = hrow[(long)sA * 16 + cc];
    bool mA = (e0 + q) < e1;

    for (int e = e0; e < e1; e += 4) {
        int eB = e + 4;
        int sB = sA; float alB = alA; uint2 hvB = hvA; bool mB = mA;
        if (eB < e1) {                    // wave-uniform branch
            int idxB = eB + q; if (idxB >= e1) idxB = e1 - 1;
            sB = srcs[idxB];
            alB = als[sB * 4 + hd];
            hvB = hrow[(long)sB * 16 + cc];
            mB = (eB + q) < e1;
        }
        float w = mA ? __expf(lrelu(alA + ad)) : 0.f;
        den += w;
        acc.x = fmaf(w, bf_lo(hvA.x), acc.x);
        acc.y = fmaf(w, bf_hi(hvA.x), acc.y);
        acc.z = fmaf(w, bf_lo(hvA.y), acc.z);
        acc.w = fmaf(w, bf_hi(hvA.y), acc.w);
        sA = sB; alA = alB; hvA = hvB; mA = mB;
    }

    acc.x += __shfl_xor(acc.x, 16); acc.y += __shfl_xor(acc.y, 16);
    acc.z += __shfl_xor(acc.z, 16); acc.w += __shfl_xor(acc.w, 16);
    den += __shfl_xor(den, 16);
    acc.x += __shfl_xor(acc.x, 32); acc.y += __shfl_xor(acc.y, 32);
    acc.z += __shfl_xor(acc.z, 32); acc.w += __shfl_xor(acc.w, 32);
    den += __shfl_xor(den, 32);
    if (q == 0) {
        // channels for this lane: 2*cc (lo/hi interleave): lane cc holds ch {4cc..4cc+3}
        float4 b4 = *reinterpret_cast<const float4*>(&bias[cc * 4]);
        float inv = 1.f / den;
        float4 o;
        o.x = fmaf(acc.x, inv, b4.x);
        o.y = fmaf(acc.y, inv, b4.y);
        o.z = fmaf(acc.z, inv, b4.z);
        o.w = fmaf(acc.w, inv, b4.w);
        if (do_relu) {
            o.x = fmaxf(o.x, 0.f); o.y = fmaxf(o.y, 0.f);
            o.z = fmaxf(o.z, 0.f); o.w = fmaxf(o.w, 0.f);
        }
        *reinterpret_cast<float4*>(&g[(long)n * 64 + cc * 4]) = o;
    }
}

// ---------------- aggregation, H=1 C=32, bf16 payload ----------------
// q=lane>>3 (8 edges/batch), cc=lane&7 (8 lanes x 8 B = full 32-ch bf16 row).
__global__ __launch_bounds__(256) void agg_h1(const int* __restrict__ cnt, const int* __restrict__ srcs,
                                              const unsigned short* __restrict__ h3, const float* __restrict__ als,
                                              const float* __restrict__ ald, const float* __restrict__ bias,
                                              float* __restrict__ out) {
    const uint2* hrow = reinterpret_cast<const uint2*>(h3);  // 8 uint2 per 32-ch row
    int wid = threadIdx.x >> 6, lane = threadIdx.x & 63;
    int n = agg_node(blockIdx.x, wid);
    if (n >= N_NODES) return;
    int q = lane >> 3, cc = lane & 7;
    float ad = ald[n];
    int deg = cnt[n]; if (deg > CAP) deg = CAP;
    int e0 = n * CAP, e1 = e0 + deg;
    float4 acc = make_float4(0.f, 0.f, 0.f, 0.f);
    float den = 0.f;

    int idxA = e0 + q; if (idxA >= e1) idxA = e1 - 1;
    int sA = srcs[idxA];
    float alA = als[sA];
    uint2 hvA = hrow[(long)sA * 8 + cc];
    bool mA = (e0 + q) < e1;

    for (int e = e0; e < e1; e += 8) {
        int eB = e + 8;
        int sB = sA; float alB = alA; uint2 hvB = hvA; bool mB = mA;
        if (eB < e1) {
            int idxB = eB + q; if (idxB >= e1) idxB = e1 - 1;
            sB = srcs[idxB];
            alB = als[sB];
            hvB = hrow[(long)sB * 8 + cc];
            mB = (eB + q) < e1;
        }
        float w = mA ? __expf(lrelu(alA + ad)) : 0.f;
        den += w;
        acc.x = fmaf(w, bf_lo(hvA.x), acc.x);
        acc.y = fmaf(w, bf_hi(hvA.x), acc.y);
        acc.z = fmaf(w, bf_lo(hvA.y), acc.z);
        acc.w = fmaf(w, bf_hi(hvA.y), acc.w);
        sA = sB; alA = alB; hvA = hvB; mA = mB;
    }

    acc.x += __shfl_xor(acc.x, 8);  acc.y += __shfl_xor(acc.y, 8);
    acc.z += __shfl_xor(acc.z, 8);  acc.w += __shfl_xor(acc.w, 8);
    den += __shfl_xor(den, 8);
    acc.x += __shfl_xor(acc.x, 16); acc.y += __shfl_xor(acc.y, 16);
    acc.z += __shfl_xor(acc.z, 16); acc.w += __shfl_xor(acc.w, 16);
    den += __shfl_xor(den, 16);
    acc.x += __shfl_xor(acc.x, 32); acc.y += __shfl_xor(acc.y, 32);
    acc.z += __shfl_xor(acc.z, 32); acc.w += __shfl_xor(acc.w, 32);
    den += __shfl_xor(den, 32);
    if (q == 0) {
        float4 b4 = *reinterpret_cast<const float4*>(&bias[cc * 4]);
        float inv = 1.f / den;
        float4 o;
        o.x = fmaf(acc.x, inv, b4.x);
        o.y = fmaf(acc.y, inv, b4.y);
        o.z = fmaf(acc.z, inv, b4.z);
        o.w = fmaf(acc.w, inv, b4.w);
        *reinterpret_cast<float4*>(&out[(long)n * 32 + cc * 4]) = o;
    }
}

extern "C" void kernel_launch(void* const* d_in, const int* in_sizes, int n_in,
                              void* d_out, int out_size, void* d_ws, size_t ws_size,
                              hipStream_t stream) {
    (void)in_sizes; (void)n_in; (void)out_size; (void)ws_size;
    const float* x   = (const float*)d_in[0];
    const int*   ei  = (const int*)d_in[1];
    const float* W1  = (const float*)d_in[2];
    const float* as1 = (const float*)d_in[3];
    const float* ad1 = (const float*)d_in[4];
    const float* b1  = (const float*)d_in[5];
    const float* W2  = (const float*)d_in[6];
    const float* as2 = (const float*)d_in[7];
    const float* ad2 = (const float*)d_in[8];
    const float* b2  = (const float*)d_in[9];
    const float* W3  = (const float*)d_in[10];
    const float* as3 = (const float*)d_in[11];
    const float* ad3 = (const float*)d_in[12];
    const float* b3  = (const float*)d_in[13];
    float* out = (float*)d_out;

    char* w = (char*)d_ws;
    auto alloc = [&](size_t bytes) {
        void* p = (void*)w;
        w += (bytes + 255) & ~(size_t)255;
        return p;
    };
    int*            cnt  = (int*)alloc((size_t)N_NODES * 4);
    int*            srcs = (int*)alloc((size_t)N_NODES * CAP * 4);   // 19.2 MB
    unsigned short* h    = (unsigned short*)alloc((size_t)N_NODES * 64 * 2);  // bf16, 12.8 MB
    float*          g    = (float*)alloc((size_t)N_NODES * 64 * 4);
    float*          als  = (float*)alloc((size_t)N_NODES * 4 * 4);
    float*          ald  = (float*)alloc((size_t)N_NODES * 4 * 4);

    hipMemsetAsync(cnt, 0, (size_t)N_NODES * 4, stream);

    int g64  = (N_NODES + 63) / 64;    // 1563
    int g128 = (N_NODES + 127) / 128;  // 782
    int gAgg = ((N_NODES + 3) / 4 + 7) & ~7;   // 25000 -> mult of 8

    bucket_scatter<<<CSR_BLOCKS, 256, 0, stream>>>(ei, cnt, srcs);

    // layer 1: x[100000,128] @ W1[128,64], H=4
    gemm_al<128, 64, 4, 64><<<g64, 256, 0, stream>>>(x, W1, as1, ad1, h, als, ald);
    agg_h4<<<gAgg, 256, 0, stream>>>(cnt, srcs, h, als, ald, b1, g, 1);
    // layer 2: g[100000,64] @ W2[64,64], H=4
    gemm_al<64, 64, 4, 64><<<g64, 256, 0, stream>>>(g, W2, as2, ad2, h, als, ald);
    agg_h4<<<gAgg, 256, 0, stream>>>(cnt, srcs, h, als, ald, b2, g, 1);
    // layer 3: g[100000,64] @ W3[64,32], H=1 -> d_out
    gemm_al<64, 32, 1, 128><<<g128, 256, 0, stream>>>(g, W3, as3, ad3, h, als, ald);
    agg_h1<<<gAgg, 256, 0, stream>>>(cnt, srcs, h, als, ald, b3, out);
}

// Round 10
// 405.243 us; speedup vs baseline: 2.0765x; 1.0372x over previous
//
#include <hip/hip_runtime.h>

#define N_NODES 100000
#define N_EDGES 1600000
#define E_TOT   (N_EDGES + N_NODES)
#define NPART   8
#define PART_SZ (N_NODES / NPART)   // 12500
#define PART_BLOCKS 256             // blocks per partition
#define CSR_BLOCKS (NPART * PART_BLOCKS)
#define CAP 48                      // bucket capacity; degree ~ Poisson(16), P(>=48) ~ 1e-9

static __device__ __forceinline__ float lrelu(float z) { return z > 0.f ? z : 0.2f * z; }

// bf16 round-to-nearest-even pack / unpack (values are finite, no NaN handling)
static __device__ __forceinline__ unsigned f2bf(float f) {
    unsigned u = __float_as_uint(f);
    u += 0x7fffu + ((u >> 16) & 1u);
    return u >> 16;
}
static __device__ __forceinline__ float bf_lo(unsigned v) { return __uint_as_float(v << 16); }
static __device__ __forceinline__ float bf_hi(unsigned v) { return __uint_as_float(v & 0xffff0000u); }

// ---------------- bucket scatter (XCD-partitioned by dst range) ----------------
__global__ __launch_bounds__(256) void bucket_scatter(const int* __restrict__ ei, int* __restrict__ cnt,
                                                      int* __restrict__ srcs) {
    int part = blockIdx.x & (NPART - 1);
    int lo = part * PART_SZ, hi = lo + PART_SZ;
    int stride = (CSR_BLOCKS / NPART) * 256;
    for (int t = (blockIdx.x / NPART) * 256 + threadIdx.x; t < E_TOT; t += stride) {
        int d = (t < N_EDGES) ? ei[N_EDGES + t] : (t - N_EDGES);
        if (d >= lo && d < hi) {
            int s = (t < N_EDGES) ? ei[t] : d;
            int slot = atomicAdd(&cnt[d], 1);
            if (slot < CAP) srcs[d * CAP + slot] = s;
        }
    }
}

// ---------------- fused GEMM + attention logits (wave-sliced, scalar W path) ----------------
// readfirstlane forces the W address chain into SGPRs -> s_load per k-row (round-6 win).
// h written as bf16 (round-9 win: halves gather traffic downstream).
template <int IN, int OUT, int HEADS, int NPB>
__global__ __launch_bounds__(256) void gemm_al(const float* __restrict__ x, const float* __restrict__ W,
                                               const float* __restrict__ asrc, const float* __restrict__ adst,
                                               unsigned short* __restrict__ h, float* __restrict__ als,
                                               float* __restrict__ ald) {
    constexpr int SPLIT = OUT / 16;
    constexpr int STRIDE = IN + 1;
    constexpr int F4PT = NPB * (IN / 4) / 256;
    __shared__ float sx[NPB * STRIDE];
    int t = threadIdx.x;
    long base = (long)blockIdx.x * NPB;

#pragma unroll
    for (int p = 0; p < F4PT; ++p) {
        int e = p * 256 + t;
        int row = e / (IN / 4);
        int c4 = e % (IN / 4);
        long gr = base + row;
        if (gr >= N_NODES) gr = N_NODES - 1;
        float4 v = *reinterpret_cast<const float4*>(&x[gr * IN + c4 * 4]);
        float* d = &sx[row * STRIDE + c4 * 4];
        d[0] = v.x; d[1] = v.y; d[2] = v.z; d[3] = v.w;
    }
    __syncthreads();

    int w = t >> 6, lane = t & 63;
    int s = __builtin_amdgcn_readfirstlane(w % SPLIT);
    int grp = __builtin_amdgcn_readfirstlane(w / SPLIT);
    int r = grp * 64 + lane;
    long n = base + r;

    float acc[16];
#pragma unroll
    for (int j = 0; j < 16; ++j) acc[j] = 0.f;

    const float* Ws = W + s * 16;
#pragma unroll 8
    for (int k = 0; k < IN; ++k) {
        float xv = sx[r * STRIDE + k];
        const float* Wr = Ws + k * OUT;
#pragma unroll
        for (int j = 0; j < 16; ++j) acc[j] = fmaf(xv, Wr[j], acc[j]);
    }

    if (n < N_NODES) {
        unsigned u[8];
#pragma unroll
        for (int k = 0; k < 8; ++k)
            u[k] = f2bf(acc[2 * k]) | (f2bf(acc[2 * k + 1]) << 16);
        uint4* dst = reinterpret_cast<uint4*>(&h[n * OUT + s * 16]);
        dst[0] = make_uint4(u[0], u[1], u[2], u[3]);
        dst[1] = make_uint4(u[4], u[5], u[6], u[7]);
    }

    float ps = 0.f, pd = 0.f;
#pragma unroll
    for (int j = 0; j < 16; ++j) {
        ps = fmaf(acc[j], asrc[s * 16 + j], ps);
        pd = fmaf(acc[j], adst[s * 16 + j], pd);
    }
    if (HEADS == SPLIT) {
        if (n < N_NODES) {
            als[n * HEADS + s] = ps;
            ald[n * HEADS + s] = pd;
        }
    } else {
        __syncthreads();
        sx[r * 2 + s] = ps;
        sx[NPB * 2 + r * 2 + s] = pd;
        __syncthreads();
        if (t < NPB) {
            long nn = base + t;
            if (nn < N_NODES) {
                als[nn] = sx[t * 2] + sx[t * 2 + 1];
                ald[nn] = sx[NPB * 2 + t * 2] + sx[NPB * 2 + t * 2 + 1];
            }
        }
    }
}

// XCD-aligned node mapping for agg: XCD k (blockIdx&7) processes dst range k.
static __device__ __forceinline__ int agg_node(int blk, int wid) {
    return (blk & 7) * PART_SZ + (blk >> 3) * 4 + wid;
}

// ---------------- aggregation, H=4 C=16, bf16 payload, uint4 lanes ----------------
// bf16 row = 128 B = 8 lanes x uint4 -> q=lane>>3 gives 8 edges in flight
// (was 4 with uint2): halves VMEM instrs/edge, doubles gather MLP.
// hd = cc>>1 (channels 8cc..8cc+7 never straddle a head boundary).
__global__ __launch_bounds__(256) void agg_h4(const int* __restrict__ cnt, const int* __restrict__ srcs,
                                              const unsigned short* __restrict__ h, const float* __restrict__ als,
                                              const float* __restrict__ ald, const float* __restrict__ bias,
                                              float* __restrict__ g, int do_relu) {
    const uint4* hrow = reinterpret_cast<const uint4*>(h);   // 8 uint4 per 64-ch row
    int wid = threadIdx.x >> 6, lane = threadIdx.x & 63;
    int n = agg_node(blockIdx.x, wid);
    if (n >= N_NODES) return;
    int q = lane >> 3, cc = lane & 7;
    int hd = cc >> 1;
    float ad = ald[n * 4 + hd];
    int deg = cnt[n]; if (deg > CAP) deg = CAP;   // deg >= 1 (self-loop)
    int e0 = n * CAP, e1 = e0 + deg;
    float a0 = 0.f, a1 = 0.f, a2 = 0.f, a3 = 0.f, a4 = 0.f, a5 = 0.f, a6 = 0.f, a7 = 0.f;
    float den = 0.f;

    int idxA = e0 + q; if (idxA >= e1) idxA = e1 - 1;
    int sA = srcs[idxA];
    float alA = als[sA * 4 + hd];
    uint4 hvA = hrow[(long)sA * 8 + cc];
    bool mA = (e0 + q) < e1;

    for (int e = e0; e < e1; e += 8) {
        int eB = e + 8;
        int sB = sA; float alB = alA; uint4 hvB = hvA; bool mB = mA;
        if (eB < e1) {                    // wave-uniform branch
            int idxB = eB + q; if (idxB >= e1) idxB = e1 - 1;
            sB = srcs[idxB];
            alB = als[sB * 4 + hd];
            hvB = hrow[(long)sB * 8 + cc];
            mB = (eB + q) < e1;
        }
        float w = mA ? __expf(lrelu(alA + ad)) : 0.f;
        den += w;
        a0 = fmaf(w, bf_lo(hvA.x), a0);
        a1 = fmaf(w, bf_hi(hvA.x), a1);
        a2 = fmaf(w, bf_lo(hvA.y), a2);
        a3 = fmaf(w, bf_hi(hvA.y), a3);
        a4 = fmaf(w, bf_lo(hvA.z), a4);
        a5 = fmaf(w, bf_hi(hvA.z), a5);
        a6 = fmaf(w, bf_lo(hvA.w), a6);
        a7 = fmaf(w, bf_hi(hvA.w), a7);
        sA = sB; alA = alB; hvA = hvB; mA = mB;
    }

#pragma unroll
    for (int d = 8; d <= 32; d <<= 1) {
        a0 += __shfl_xor(a0, d); a1 += __shfl_xor(a1, d);
        a2 += __shfl_xor(a2, d); a3 += __shfl_xor(a3, d);
        a4 += __shfl_xor(a4, d); a5 += __shfl_xor(a5, d);
        a6 += __shfl_xor(a6, d); a7 += __shfl_xor(a7, d);
        den += __shfl_xor(den, d);
    }
    if (q == 0) {
        float4 b0 = *reinterpret_cast<const float4*>(&bias[cc * 8]);
        float4 b1 = *reinterpret_cast<const float4*>(&bias[cc * 8 + 4]);
        float inv = 1.f / den;
        float4 o0, o1;
        o0.x = fmaf(a0, inv, b0.x); o0.y = fmaf(a1, inv, b0.y);
        o0.z = fmaf(a2, inv, b0.z); o0.w = fmaf(a3, inv, b0.w);
        o1.x = fmaf(a4, inv, b1.x); o1.y = fmaf(a5, inv, b1.y);
        o1.z = fmaf(a6, inv, b1.z); o1.w = fmaf(a7, inv, b1.w);
        if (do_relu) {
            o0.x = fmaxf(o0.x, 0.f); o0.y = fmaxf(o0.y, 0.f);
            o0.z = fmaxf(o0.z, 0.f); o0.w = fmaxf(o0.w, 0.f);
            o1.x = fmaxf(o1.x, 0.f); o1.y = fmaxf(o1.y, 0.f);
            o1.z = fmaxf(o1.z, 0.f); o1.w = fmaxf(o1.w, 0.f);
        }
        *reinterpret_cast<float4*>(&g[(long)n * 64 + cc * 8]) = o0;
        *reinterpret_cast<float4*>(&g[(long)n * 64 + cc * 8 + 4]) = o1;
    }
}

// ---------------- aggregation, H=1 C=32, bf16 payload, uint4 lanes ----------------
// 32-ch bf16 row = 64 B = 4 lanes x uint4 -> q=lane>>2 gives 16 edges in flight.
__global__ __launch_bounds__(256) void agg_h1(const int* __restrict__ cnt, const int* __restrict__ srcs,
                                              const unsigned short* __restrict__ h3, const float* __restrict__ als,
                                              const float* __restrict__ ald, const float* __restrict__ bias,
                                              float* __restrict__ out) {
    const uint4* hrow = reinterpret_cast<const uint4*>(h3);  // 4 uint4 per 32-ch row
    int wid = threadIdx.x >> 6, lane = threadIdx.x & 63;
    int n = agg_node(blockIdx.x, wid);
    if (n >= N_NODES) return;
    int q = lane >> 2, cc = lane & 3;
    float ad = ald[n];
    int deg = cnt[n]; if (deg > CAP) deg = CAP;
    int e0 = n * CAP, e1 = e0 + deg;
    float a0 = 0.f, a1 = 0.f, a2 = 0.f, a3 = 0.f, a4 = 0.f, a5 = 0.f, a6 = 0.f, a7 = 0.f;
    float den = 0.f;

    int idxA = e0 + q; if (idxA >= e1) idxA = e1 - 1;
    int sA = srcs[idxA];
    float alA = als[sA];
    uint4 hvA = hrow[(long)sA * 4 + cc];
    bool mA = (e0 + q) < e1;

    for (int e = e0; e < e1; e += 16) {
        int eB = e + 16;
        int sB = sA; float alB = alA; uint4 hvB = hvA; bool mB = mA;
        if (eB < e1) {
            int idxB = eB + q; if (idxB >= e1) idxB = e1 - 1;
            sB = srcs[idxB];
            alB = als[sB];
            hvB = hrow[(long)sB * 4 + cc];
            mB = (eB + q) < e1;
        }
        float w = mA ? __expf(lrelu(alA + ad)) : 0.f;
        den += w;
        a0 = fmaf(w, bf_lo(hvA.x), a0);
        a1 = fmaf(w, bf_hi(hvA.x), a1);
        a2 = fmaf(w, bf_lo(hvA.y), a2);
        a3 = fmaf(w, bf_hi(hvA.y), a3);
        a4 = fmaf(w, bf_lo(hvA.z), a4);
        a5 = fmaf(w, bf_hi(hvA.z), a5);
        a6 = fmaf(w, bf_lo(hvA.w), a6);
        a7 = fmaf(w, bf_hi(hvA.w), a7);
        sA = sB; alA = alB; hvA = hvB; mA = mB;
    }

#pragma unroll
    for (int d = 4; d <= 32; d <<= 1) {
        a0 += __shfl_xor(a0, d); a1 += __shfl_xor(a1, d);
        a2 += __shfl_xor(a2, d); a3 += __shfl_xor(a3, d);
        a4 += __shfl_xor(a4, d); a5 += __shfl_xor(a5, d);
        a6 += __shfl_xor(a6, d); a7 += __shfl_xor(a7, d);
        den += __shfl_xor(den, d);
    }
    if (q == 0) {
        float4 b0 = *reinterpret_cast<const float4*>(&bias[cc * 8]);
        float4 b1 = *reinterpret_cast<const float4*>(&bias[cc * 8 + 4]);
        float inv = 1.f / den;
        float4 o0, o1;
        o0.x = fmaf(a0, inv, b0.x); o0.y = fmaf(a1, inv, b0.y);
        o0.z = fmaf(a2, inv, b0.z); o0.w = fmaf(a3, inv, b0.w);
        o1.x = fmaf(a4, inv, b1.x); o1.y = fmaf(a5, inv, b1.y);
        o1.z = fmaf(a6, inv, b1.z); o1.w = fmaf(a7, inv, b1.w);
        *reinterpret_cast<float4*>(&out[(long)n * 32 + cc * 8]) = o0;
        *reinterpret_cast<float4*>(&out[(long)n * 32 + cc * 8 + 4]) = o1;
    }
}

extern "C" void kernel_launch(void* const* d_in, const int* in_sizes, int n_in,
                              void* d_out, int out_size, void* d_ws, size_t ws_size,
                              hipStream_t stream) {
    (void)in_sizes; (void)n_in; (void)out_size; (void)ws_size;
    const float* x   = (const float*)d_in[0];
    const int*   ei  = (const int*)d_in[1];
    const float* W1  = (const float*)d_in[2];
    const float* as1 = (const float*)d_in[3];
    const float* ad1 = (const float*)d_in[4];
    const float* b1  = (const float*)d_in[5];
    const float* W2  = (const float*)d_in[6];
    const float* as2 = (const float*)d_in[7];
    const float* ad2 = (const float*)d_in[8];
    const float* b2  = (const float*)d_in[9];
    const float* W3  = (const float*)d_in[10];
    const float* as3 = (const float*)d_in[11];
    const float* ad3 = (const float*)d_in[12];
    const float* b3  = (const float*)d_in[13];
    float* out = (float*)d_out;

    char* w = (char*)d_ws;
    auto alloc = [&](size_t bytes) {
        void* p = (void*)w;
        w += (bytes + 255) & ~(size_t)255;
        return p;
    };
    int*            cnt  = (int*)alloc((size_t)N_NODES * 4);
    int*            srcs = (int*)alloc((size_t)N_NODES * CAP * 4);   // 19.2 MB
    unsigned short* h    = (unsigned short*)alloc((size_t)N_NODES * 64 * 2);  // bf16, 12.8 MB
    float*          g    = (float*)alloc((size_t)N_NODES * 64 * 4);
    float*          als  = (float*)alloc((size_t)N_NODES * 4 * 4);
    float*          ald  = (float*)alloc((size_t)N_NODES * 4 * 4);

    hipMemsetAsync(cnt, 0, (size_t)N_NODES * 4, stream);

    int g64  = (N_NODES + 63) / 64;    // 1563
    int g128 = (N_NODES + 127) / 128;  // 782
    int gAgg = ((N_NODES + 3) / 4 + 7) & ~7;   // 25000 -> mult of 8

    bucket_scatter<<<CSR_BLOCKS, 256, 0, stream>>>(ei, cnt, srcs);

    // layer 1: x[100000,128] @ W1[128,64], H=4
    gemm_al<128, 64, 4, 64><<<g64, 256, 0, stream>>>(x, W1, as1, ad1, h, als, ald);
    agg_h4<<<gAgg, 256, 0, stream>>>(cnt, srcs, h, als, ald, b1, g, 1);
    // layer 2: g[100000,64] @ W2[64,64], H=4
    gemm_al<64, 64, 4, 64><<<g64, 256, 0, stream>>>(g, W2, as2, ad2, h, als, ald);
    agg_h4<<<gAgg, 256, 0, stream>>>(cnt, srcs, h, als, ald, b2, g, 1);
    // layer 3: g[100000,64] @ W3[64,32], H=1 -> d_out
    gemm_al<64, 32, 1, 128><<<g128, 256, 0, stream>>>(g, W3, as3, ad3, h, als, ald);
    agg_h1<<<gAgg, 256, 0, stream>>>(cnt, srcs, h, als, ald, b3, out);
}

// Round 11
// 401.495 us; speedup vs baseline: 2.0958x; 1.0093x over previous
//
#include <hip/hip_runtime.h>

#define N_NODES 100000
#define N_EDGES 1600000
#define E_TOT   (N_EDGES + N_NODES)
#define NPART   8
#define PART_SZ (N_NODES / NPART)   // 12500
#define PART_BLOCKS 256             // blocks per partition
#define CSR_BLOCKS (NPART * PART_BLOCKS)
#define CAP 48                      // bucket capacity; degree ~ Poisson(16), P(>=48) ~ 1e-9

static __device__ __forceinline__ float lrelu(float z) { return z > 0.f ? z : 0.2f * z; }

// bf16 round-to-nearest-even pack / unpack (values are finite, no NaN handling)
static __device__ __forceinline__ unsigned f2bf(float f) {
    unsigned u = __float_as_uint(f);
    u += 0x7fffu + ((u >> 16) & 1u);
    return u >> 16;
}
static __device__ __forceinline__ float bf_lo(unsigned v) { return __uint_as_float(v << 16); }
static __device__ __forceinline__ float bf_hi(unsigned v) { return __uint_as_float(v & 0xffff0000u); }

// ---------------- bucket scatter (XCD-partitioned by dst range) ----------------
// Round-10 pathology: WRITE_SIZE 81 MB vs 19.6 MB logical — the per-XCD ei
// stream (12.8 MB/scan) evicted partially-filled bucket lines over and over.
// Fix: non-temporal ei loads (no L2 allocate) -> the 2.4 MB bucket region +
// 50 KB cnt slice stay L2-resident; each bucket line writes back once.
__global__ __launch_bounds__(256) void bucket_scatter(const int* __restrict__ ei, int* __restrict__ cnt,
                                                      int* __restrict__ srcs) {
    int part = blockIdx.x & (NPART - 1);
    int lo = part * PART_SZ, hi = lo + PART_SZ;
    int stride = (CSR_BLOCKS / NPART) * 256;
    for (int t = (blockIdx.x / NPART) * 256 + threadIdx.x; t < E_TOT; t += stride) {
        int d = (t < N_EDGES) ? __builtin_nontemporal_load(ei + N_EDGES + t) : (t - N_EDGES);
        if (d >= lo && d < hi) {
            int s = (t < N_EDGES) ? __builtin_nontemporal_load(ei + t) : d;
            int slot = atomicAdd(&cnt[d], 1);
            if (slot < CAP) srcs[d * CAP + slot] = s;
        }
    }
}

// ---------------- fused GEMM + attention logits (wave-sliced, scalar W path) ----------------
// readfirstlane forces the W address chain into SGPRs -> s_load per k-row (round-6 win).
// h written as bf16 (round-9 win: halves gather traffic downstream).
template <int IN, int OUT, int HEADS, int NPB>
__global__ __launch_bounds__(256) void gemm_al(const float* __restrict__ x, const float* __restrict__ W,
                                               const float* __restrict__ asrc, const float* __restrict__ adst,
                                               unsigned short* __restrict__ h, float* __restrict__ als,
                                               float* __restrict__ ald) {
    constexpr int SPLIT = OUT / 16;
    constexpr int STRIDE = IN + 1;
    constexpr int F4PT = NPB * (IN / 4) / 256;
    __shared__ float sx[NPB * STRIDE];
    int t = threadIdx.x;
    long base = (long)blockIdx.x * NPB;

#pragma unroll
    for (int p = 0; p < F4PT; ++p) {
        int e = p * 256 + t;
        int row = e / (IN / 4);
        int c4 = e % (IN / 4);
        long gr = base + row;
        if (gr >= N_NODES) gr = N_NODES - 1;
        float4 v = *reinterpret_cast<const float4*>(&x[gr * IN + c4 * 4]);
        float* d = &sx[row * STRIDE + c4 * 4];
        d[0] = v.x; d[1] = v.y; d[2] = v.z; d[3] = v.w;
    }
    __syncthreads();

    int w = t >> 6, lane = t & 63;
    int s = __builtin_amdgcn_readfirstlane(w % SPLIT);
    int grp = __builtin_amdgcn_readfirstlane(w / SPLIT);
    int r = grp * 64 + lane;
    long n = base + r;

    float acc[16];
#pragma unroll
    for (int j = 0; j < 16; ++j) acc[j] = 0.f;

    const float* Ws = W + s * 16;
#pragma unroll 8
    for (int k = 0; k < IN; ++k) {
        float xv = sx[r * STRIDE + k];
        const float* Wr = Ws + k * OUT;
#pragma unroll
        for (int j = 0; j < 16; ++j) acc[j] = fmaf(xv, Wr[j], acc[j]);
    }

    if (n < N_NODES) {
        unsigned u[8];
#pragma unroll
        for (int k = 0; k < 8; ++k)
            u[k] = f2bf(acc[2 * k]) | (f2bf(acc[2 * k + 1]) << 16);
        uint4* dst = reinterpret_cast<uint4*>(&h[n * OUT + s * 16]);
        dst[0] = make_uint4(u[0], u[1], u[2], u[3]);
        dst[1] = make_uint4(u[4], u[5], u[6], u[7]);
    }

    float ps = 0.f, pd = 0.f;
#pragma unroll
    for (int j = 0; j < 16; ++j) {
        ps = fmaf(acc[j], asrc[s * 16 + j], ps);
        pd = fmaf(acc[j], adst[s * 16 + j], pd);
    }
    if (HEADS == SPLIT) {
        if (n < N_NODES) {
            als[n * HEADS + s] = ps;
            ald[n * HEADS + s] = pd;
        }
    } else {
        __syncthreads();
        sx[r * 2 + s] = ps;
        sx[NPB * 2 + r * 2 + s] = pd;
        __syncthreads();
        if (t < NPB) {
            long nn = base + t;
            if (nn < N_NODES) {
                als[nn] = sx[t * 2] + sx[t * 2 + 1];
                ald[nn] = sx[NPB * 2 + t * 2] + sx[NPB * 2 + t * 2 + 1];
            }
        }
    }
}

// XCD-aligned node mapping for agg: XCD k (blockIdx&7) processes dst range k.
static __device__ __forceinline__ int agg_node(int blk, int wid) {
    return (blk & 7) * PART_SZ + (blk >> 3) * 4 + wid;
}

// ---------------- aggregation, H=4 C=16, bf16 payload, uint4 lanes ----------------
// bf16 row = 128 B = 8 lanes x uint4 -> q=lane>>3 gives 8 edges in flight.
__global__ __launch_bounds__(256) void agg_h4(const int* __restrict__ cnt, const int* __restrict__ srcs,
                                              const unsigned short* __restrict__ h, const float* __restrict__ als,
                                              const float* __restrict__ ald, const float* __restrict__ bias,
                                              float* __restrict__ g, int do_relu) {
    const uint4* hrow = reinterpret_cast<const uint4*>(h);   // 8 uint4 per 64-ch row
    int wid = threadIdx.x >> 6, lane = threadIdx.x & 63;
    int n = agg_node(blockIdx.x, wid);
    if (n >= N_NODES) return;
    int q = lane >> 3, cc = lane & 7;
    int hd = cc >> 1;
    float ad = ald[n * 4 + hd];
    int deg = cnt[n]; if (deg > CAP) deg = CAP;   // deg >= 1 (self-loop)
    int e0 = n * CAP, e1 = e0 + deg;
    float a0 = 0.f, a1 = 0.f, a2 = 0.f, a3 = 0.f, a4 = 0.f, a5 = 0.f, a6 = 0.f, a7 = 0.f;
    float den = 0.f;

    int idxA = e0 + q; if (idxA >= e1) idxA = e1 - 1;
    int sA = srcs[idxA];
    float alA = als[sA * 4 + hd];
    uint4 hvA = hrow[(long)sA * 8 + cc];
    bool mA = (e0 + q) < e1;

    for (int e = e0; e < e1; e += 8) {
        int eB = e + 8;
        int sB = sA; float alB = alA; uint4 hvB = hvA; bool mB = mA;
        if (eB < e1) {                    // wave-uniform branch
            int idxB = eB + q; if (idxB >= e1) idxB = e1 - 1;
            sB = srcs[idxB];
            alB = als[sB * 4 + hd];
            hvB = hrow[(long)sB * 8 + cc];
            mB = (eB + q) < e1;
        }
        float w = mA ? __expf(lrelu(alA + ad)) : 0.f;
        den += w;
        a0 = fmaf(w, bf_lo(hvA.x), a0);
        a1 = fmaf(w, bf_hi(hvA.x), a1);
        a2 = fmaf(w, bf_lo(hvA.y), a2);
        a3 = fmaf(w, bf_hi(hvA.y), a3);
        a4 = fmaf(w, bf_lo(hvA.z), a4);
        a5 = fmaf(w, bf_hi(hvA.z), a5);
        a6 = fmaf(w, bf_lo(hvA.w), a6);
        a7 = fmaf(w, bf_hi(hvA.w), a7);
        sA = sB; alA = alB; hvA = hvB; mA = mB;
    }

#pragma unroll
    for (int d = 8; d <= 32; d <<= 1) {
        a0 += __shfl_xor(a0, d); a1 += __shfl_xor(a1, d);
        a2 += __shfl_xor(a2, d); a3 += __shfl_xor(a3, d);
        a4 += __shfl_xor(a4, d); a5 += __shfl_xor(a5, d);
        a6 += __shfl_xor(a6, d); a7 += __shfl_xor(a7, d);
        den += __shfl_xor(den, d);
    }
    if (q == 0) {
        float4 b0 = *reinterpret_cast<const float4*>(&bias[cc * 8]);
        float4 b1 = *reinterpret_cast<const float4*>(&bias[cc * 8 + 4]);
        float inv = 1.f / den;
        float4 o0, o1;
        o0.x = fmaf(a0, inv, b0.x); o0.y = fmaf(a1, inv, b0.y);
        o0.z = fmaf(a2, inv, b0.z); o0.w = fmaf(a3, inv, b0.w);
        o1.x = fmaf(a4, inv, b1.x); o1.y = fmaf(a5, inv, b1.y);
        o1.z = fmaf(a6, inv, b1.z); o1.w = fmaf(a7, inv, b1.w);
        if (do_relu) {
            o0.x = fmaxf(o0.x, 0.f); o0.y = fmaxf(o0.y, 0.f);
            o0.z = fmaxf(o0.z, 0.f); o0.w = fmaxf(o0.w, 0.f);
            o1.x = fmaxf(o1.x, 0.f); o1.y = fmaxf(o1.y, 0.f);
            o1.z = fmaxf(o1.z, 0.f); o1.w = fmaxf(o1.w, 0.f);
        }
        *reinterpret_cast<float4*>(&g[(long)n * 64 + cc * 8]) = o0;
        *reinterpret_cast<float4*>(&g[(long)n * 64 + cc * 8 + 4]) = o1;
    }
}

// ---------------- aggregation, H=1 C=32, bf16 payload, uint4 lanes ----------------
// 32-ch bf16 row = 64 B = 4 lanes x uint4 -> q=lane>>2 gives 16 edges in flight.
__global__ __launch_bounds__(256) void agg_h1(const int* __restrict__ cnt, const int* __restrict__ srcs,
                                              const unsigned short* __restrict__ h3, const float* __restrict__ als,
                                              const float* __restrict__ ald, const float* __restrict__ bias,
                                              float* __restrict__ out) {
    const uint4* hrow = reinterpret_cast<const uint4*>(h3);  // 4 uint4 per 32-ch row
    int wid = threadIdx.x >> 6, lane = threadIdx.x & 63;
    int n = agg_node(blockIdx.x, wid);
    if (n >= N_NODES) return;
    int q = lane >> 2, cc = lane & 3;
    float ad = ald[n];
    int deg = cnt[n]; if (deg > CAP) deg = CAP;
    int e0 = n * CAP, e1 = e0 + deg;
    float a0 = 0.f, a1 = 0.f, a2 = 0.f, a3 = 0.f, a4 = 0.f, a5 = 0.f, a6 = 0.f, a7 = 0.f;
    float den = 0.f;

    int idxA = e0 + q; if (idxA >= e1) idxA = e1 - 1;
    int sA = srcs[idxA];
    float alA = als[sA];
    uint4 hvA = hrow[(long)sA * 4 + cc];
    bool mA = (e0 + q) < e1;

    for (int e = e0; e < e1; e += 16) {
        int eB = e + 16;
        int sB = sA; float alB = alA; uint4 hvB = hvA; bool mB = mA;
        if (eB < e1) {
            int idxB = eB + q; if (idxB >= e1) idxB = e1 - 1;
            sB = srcs[idxB];
            alB = als[sB];
            hvB = hrow[(long)sB * 4 + cc];
            mB = (eB + q) < e1;
        }
        float w = mA ? __expf(lrelu(alA + ad)) : 0.f;
        den += w;
        a0 = fmaf(w, bf_lo(hvA.x), a0);
        a1 = fmaf(w, bf_hi(hvA.x), a1);
        a2 = fmaf(w, bf_lo(hvA.y), a2);
        a3 = fmaf(w, bf_hi(hvA.y), a3);
        a4 = fmaf(w, bf_lo(hvA.z), a4);
        a5 = fmaf(w, bf_hi(hvA.z), a5);
        a6 = fmaf(w, bf_lo(hvA.w), a6);
        a7 = fmaf(w, bf_hi(hvA.w), a7);
        sA = sB; alA = alB; hvA = hvB; mA = mB;
    }

#pragma unroll
    for (int d = 4; d <= 32; d <<= 1) {
        a0 += __shfl_xor(a0, d); a1 += __shfl_xor(a1, d);
        a2 += __shfl_xor(a2, d); a3 += __shfl_xor(a3, d);
        a4 += __shfl_xor(a4, d); a5 += __shfl_xor(a5, d);
        a6 += __shfl_xor(a6, d); a7 += __shfl_xor(a7, d);
        den += __shfl_xor(den, d);
    }
    if (q == 0) {
        float4 b0 = *reinterpret_cast<const float4*>(&bias[cc * 8]);
        float4 b1 = *reinterpret_cast<const float4*>(&bias[cc * 8 + 4]);
        float inv = 1.f / den;
        float4 o0, o1;
        o0.x = fmaf(a0, inv, b0.x); o0.y = fmaf(a1, inv, b0.y);
        o0.z = fmaf(a2, inv, b0.z); o0.w = fmaf(a3, inv, b0.w);
        o1.x = fmaf(a4, inv, b1.x); o1.y = fmaf(a5, inv, b1.y);
        o1.z = fmaf(a6, inv, b1.z); o1.w = fmaf(a7, inv, b1.w);
        *reinterpret_cast<float4*>(&out[(long)n * 32 + cc * 8]) = o0;
        *reinterpret_cast<float4*>(&out[(long)n * 32 + cc * 8 + 4]) = o1;
    }
}

extern "C" void kernel_launch(void* const* d_in, const int* in_sizes, int n_in,
                              void* d_out, int out_size, void* d_ws, size_t ws_size,
                              hipStream_t stream) {
    (void)in_sizes; (void)n_in; (void)out_size; (void)ws_size;
    const float* x   = (const float*)d_in[0];
    const int*   ei  = (const int*)d_in[1];
    const float* W1  = (const float*)d_in[2];
    const float* as1 = (const float*)d_in[3];
    const float* ad1 = (const float*)d_in[4];
    const float* b1  = (const float*)d_in[5];
    const float* W2  = (const float*)d_in[6];
    const float* as2 = (const float*)d_in[7];
    const float* ad2 = (const float*)d_in[8];
    const float* b2  = (const float*)d_in[9];
    const float* W3  = (const float*)d_in[10];
    const float* as3 = (const float*)d_in[11];
    const float* ad3 = (const float*)d_in[12];
    const float* b3  = (const float*)d_in[13];
    float* out = (float*)d_out;

    char* w = (char*)d_ws;
    auto alloc = [&](size_t bytes) {
        void* p = (void*)w;
        w += (bytes + 255) & ~(size_t)255;
        return p;
    };
    int*            cnt  = (int*)alloc((size_t)N_NODES * 4);
    int*            srcs = (int*)alloc((size_t)N_NODES * CAP * 4);   // 19.2 MB
    unsigned short* h    = (unsigned short*)alloc((size_t)N_NODES * 64 * 2);  // bf16, 12.8 MB
    float*          g    = (float*)alloc((size_t)N_NODES * 64 * 4);
    float*          als  = (float*)alloc((size_t)N_NODES * 4 * 4);
    float*          ald  = (float*)alloc((size_t)N_NODES * 4 * 4);

    hipMemsetAsync(cnt, 0, (size_t)N_NODES * 4, stream);

    int g64  = (N_NODES + 63) / 64;    // 1563
    int g128 = (N_NODES + 127) / 128;  // 782
    int gAgg = ((N_NODES + 3) / 4 + 7) & ~7;   // 25000 -> mult of 8

    bucket_scatter<<<CSR_BLOCKS, 256, 0, stream>>>(ei, cnt, srcs);

    // layer 1: x[100000,128] @ W1[128,64], H=4
    gemm_al<128, 64, 4, 64><<<g64, 256, 0, stream>>>(x, W1, as1, ad1, h, als, ald);
    agg_h4<<<gAgg, 256, 0, stream>>>(cnt, srcs, h, als, ald, b1, g, 1);
    // layer 2: g[100000,64] @ W2[64,64], H=4
    gemm_al<64, 64, 4, 64><<<g64, 256, 0, stream>>>(g, W2, as2, ad2, h, als, ald);
    agg_h4<<<gAgg, 256, 0, stream>>>(cnt, srcs, h, als, ald, b2, g, 1);
    // layer 3: g[100000,64] @ W3[64,32], H=1 -> d_out
    gemm_al<64, 32, 1, 128><<<g128, 256, 0, stream>>>(g, W3, as3, ad3, h, als, ald);
    agg_h1<<<gAgg, 256, 0, stream>>>(cnt, srcs, h, als, ald, b3, out);
}